// Round 6
// baseline (135.983 us; speedup 1.0000x reference)
//
#include <hip/hip_runtime.h>
#include <math.h>

typedef __bf16 bf16x8 __attribute__((ext_vector_type(8)));
typedef float  f32x4  __attribute__((ext_vector_type(4)));
typedef int    int4v  __attribute__((ext_vector_type(4)));

constexpr float MARGIN    = 0.1f;
constexpr float SCALE_POS = 2.0f;
constexpr float SCALE_NEG = 50.0f;
constexpr float THRESH    = 0.5f;
constexpr float ONE_EPS   = 1.0f - 1e-5f;
constexpr float LOG2E     = 1.4426950408889634f;
constexpr float BC        = -(SCALE_NEG * THRESH * LOG2E);   // -36.0674
// elements with a*v + BC < -30 contribute < 2^-30 ~ 9e-10 each to neg_sum;
// total skipped mass <= 8192*9e-10/50 ~ 1.6e-7 on the loss (threshold 2e-2).
constexpr float VCUT_COEF = (36.0674f - 30.0f) / (SCALE_NEG * LOG2E);  // ~0.08412 (in S units)

constexpr int D      = 192;   // feature dim
constexpr int KS     = 6;     // 192 / 32 k-steps
constexpr int RT     = 4;     // row-tiles (16 rows) per wave
constexpr int RPW    = 64;    // rows per wave
constexpr int RPB    = 256;   // rows per block (4 waves)
constexpr int CSPLIT = 32;    // column splits (grid = 32 rowblocks x 32 = 1024 WGs = 4/CU)

// packed fragment layout: pk[((tile*KS + ks)*64 + lane)*8] shorts, where
// tile = row/16, lane = q*16+c holds bf16[row=tile*16+c][k=ks*32+q*8 .. +8).
// One wave fragment load = contiguous 1KB global_load_dwordx4.
constexpr int TILE_SH = KS * 64 * 8;   // 3072 shorts = 6KB per 16-row tile

__device__ inline short f2bf(float x) {
  unsigned u = __float_as_uint(x);
  u += 0x7fffu + ((u >> 16) & 1u);      // RNE
  return (short)(u >> 16);
}

__device__ inline float fast_exp2(float x) {
#if __has_builtin(__builtin_amdgcn_exp2f)
  return __builtin_amdgcn_exp2f(x);
#else
  return exp2f(x);
#endif
}

// ---------------- fused cast fp32->bf16 + pack into fragment layout ----------------
__global__ void k_pack(const float* __restrict__ f, short* __restrict__ pk, int total8) {
  int tid = blockIdx.x * blockDim.x + threadIdx.x;
  if (tid >= total8) return;
  int row = tid / 24;
  int j   = tid - row * 24;
  const float* src = f + (size_t)tid * 8;
  float4 a = *(const float4*)(src);
  float4 b = *(const float4*)(src + 4);
  union { short s[8]; int4v v; } o;
  o.s[0] = f2bf(a.x); o.s[1] = f2bf(a.y); o.s[2] = f2bf(a.z); o.s[3] = f2bf(a.w);
  o.s[4] = f2bf(b.x); o.s[5] = f2bf(b.y); o.s[6] = f2bf(b.z); o.s[7] = f2bf(b.w);
  int idx = (((row >> 4) * KS + (j >> 2)) * 64 + (j & 3) * 16 + (row & 15)) * 8;
  *(int4v*)(pk + idx) = o.v;
}

// ---------------- buckets: hist + scan + scatter + accum-zero, one block ----------------
__global__ __launch_bounds__(1024) void k_buckets(
    const int* __restrict__ labs, int* __restrict__ hist_g, int* __restrict__ offs_g,
    int* __restrict__ bucket, float* __restrict__ accum, int n)
{
  __shared__ int histL[4096];
  __shared__ int offsL[4096];
  __shared__ int scanb[1024];
  const int t = threadIdx.x;

  if (t < 2) accum[t] = 0.f;
  for (int i = t; i < 4096; i += 1024) histL[i] = 0;
  __syncthreads();
  for (int i = t; i < n; i += 1024) atomicAdd(&histL[labs[i]], 1);
  __syncthreads();
  int base = t * 4;
  int v[4]; int ls = 0;
  for (int k = 0; k < 4; ++k) { v[k] = ls; ls += histL[base + k]; }
  scanb[t] = ls;
  __syncthreads();
  for (int o = 1; o < 1024; o <<= 1) {
    int x = (t >= o) ? scanb[t - o] : 0;
    __syncthreads();
    scanb[t] += x;
    __syncthreads();
  }
  int ebase = scanb[t] - ls;
  for (int k = 0; k < 4; ++k) {
    offsL[base + k] = ebase + v[k];
    offs_g[base + k] = ebase + v[k];
    hist_g[base + k] = histL[base + k];
  }
  __syncthreads();
  for (int i = t; i < 4096; i += 1024) histL[i] = 0;
  __syncthreads();
  for (int i = t; i < n; i += 1024) {
    int lab = labs[i];
    int p = atomicAdd(&histL[lab], 1);
    bucket[offsL[lab] + p] = i;
  }
}

// ---------------- pass 1: sumsq + max over negatives ----------------
__global__ __launch_bounds__(256, 2) void k_pass1(
    const short* __restrict__ pk, const int* __restrict__ labs,
    float* __restrict__ sumsqP, float* __restrict__ maxnegP,
    int N, int cps)
{
  const int lane = threadIdx.x & 63;
  const int w    = threadIdx.x >> 6;
  const int q    = lane >> 4;
  const int c    = lane & 15;
  const int cs   = blockIdx.x & (CSPLIT - 1);
  const int rbb  = blockIdx.x / CSPLIT;
  const int rowbase = rbb * RPB + w * RPW;
  const int col0 = cs * cps;

  bf16x8 afr[RT][KS];
#pragma unroll
  for (int rt = 0; rt < RT; ++rt)
#pragma unroll
    for (int ks = 0; ks < KS; ++ks)
      afr[rt][ks] = *(const bf16x8*)(pk + (size_t)((rowbase >> 4) + rt) * TILE_SH + (ks * 64 + lane) * 8);

  int labrow[RT][4];
#pragma unroll
  for (int rt = 0; rt < RT; ++rt)
#pragma unroll
    for (int rr = 0; rr < 4; ++rr)
      labrow[rt][rr] = labs[(rowbase + rt * 16 + q * 4 + rr) >> 1];

  float ssq[RT][4], mxn[RT][4];
#pragma unroll
  for (int rt = 0; rt < RT; ++rt)
#pragma unroll
    for (int rr = 0; rr < 4; ++rr) { ssq[rt][rr] = 0.f; mxn[rt][rr] = -INFINITY; }

  const short* bp = pk + (size_t)(col0 >> 4) * TILE_SH + lane * 8;
  for (int ct = 0; ct < cps; ct += 16, bp += TILE_SH) {
    const int labcol = labs[(col0 + ct + c) >> 1];
    bf16x8 bfr[KS];
#pragma unroll
    for (int ks = 0; ks < KS; ++ks) bfr[ks] = *(const bf16x8*)(bp + ks * 512);
    f32x4 acc[RT];
#pragma unroll
    for (int rt = 0; rt < RT; ++rt) acc[rt] = 0.f;
#pragma unroll
    for (int ks = 0; ks < KS; ++ks)
#pragma unroll
      for (int rt = 0; rt < RT; ++rt)
        acc[rt] = __builtin_amdgcn_mfma_f32_16x16x32_bf16(afr[rt][ks], bfr[ks], acc[rt], 0, 0, 0);
#pragma unroll
    for (int rt = 0; rt < RT; ++rt)
#pragma unroll
      for (int rr = 0; rr < 4; ++rr) {
        float v = acc[rt][rr];
        ssq[rt][rr] = fmaf(v, v, ssq[rt][rr]);
        float vm = (labrow[rt][rr] == labcol) ? -INFINITY : v;
        mxn[rt][rr] = fmaxf(mxn[rt][rr], vm);
      }
  }

#pragma unroll
  for (int rt = 0; rt < RT; ++rt)
#pragma unroll
    for (int rr = 0; rr < 4; ++rr) {
      float s = ssq[rt][rr], m = mxn[rt][rr];
#pragma unroll
      for (int msk = 1; msk < 16; msk <<= 1) {
        s += __shfl_xor(s, msk, 64);
        m = fmaxf(m, __shfl_xor(m, msk, 64));
      }
      if (c == 0) {
        int row = rowbase + rt * 16 + q * 4 + rr;
        sumsqP[(size_t)cs * N + row] = s;
        maxnegP[(size_t)cs * N + row] = m;
      }
    }
}

// ---------------- per-row stats: norm, min_pos (bucket dots), pos_sum, flags ----------------
__global__ void k_rowstats(
    const float* __restrict__ f, const int* __restrict__ labs,
    const float* __restrict__ sumsqP, const float* __restrict__ maxnegP,
    const int* __restrict__ offs, const int* __restrict__ hist, const int* __restrict__ bucket,
    float* __restrict__ nthr2, float* __restrict__ arow,
    float* __restrict__ validf, float* __restrict__ hasnegf, float* __restrict__ posloss,
    int N)
{
  const int lane = threadIdx.x & 63;
  const int row  = blockIdx.x * 4 + (threadIdx.x >> 6);

  float s = 0.f, m = -INFINITY;
  if (lane < CSPLIT) {
    s = sumsqP[(size_t)lane * N + row];
    m = maxnegP[(size_t)lane * N + row];
  }
#pragma unroll
  for (int msk = 1; msk < 64; msk <<= 1) {
    s += __shfl_xor(s, msk, 64);
    m = fmaxf(m, __shfl_xor(m, msk, 64));
  }
  float nrm = fmaxf(sqrtf(s), 1e-12f);
  float inv = 1.0f / nrm;
  float maxnegS = m * inv;
  float posth = fminf(ONE_EPS, maxnegS + MARGIN);

  const int lab = labs[row >> 1];
  const int beg = offs[lab], cnt = hist[lab];
  const float* fi = f + (size_t)row * D;
  float x0 = fi[lane], x1 = fi[lane + 64], x2 = fi[lane + 128];

  float minp = INFINITY, psum = 0.f; int pcnt = 0;
  for (int t = 0; t < cnt; ++t) {
    int smp = bucket[beg + t];
#pragma unroll
    for (int u = 0; u < 2; ++u) {
      const float* fj = f + (size_t)(smp * 2 + u) * D;
      float p = x0 * fj[lane] + x1 * fj[lane + 64] + x2 * fj[lane + 128];
#pragma unroll
      for (int msk = 1; msk < 64; msk <<= 1) p += __shfl_xor(p, msk, 64);
      minp = fminf(minp, p);
      float S = p * inv;
      if (S < posth) {
        psum += fast_exp2((THRESH - S) * (SCALE_POS * LOG2E));
        pcnt++;
      }
    }
  }

  float minS = minp * inv;
  float min_pos = (minS < ONE_EPS) ? minS : INFINITY;
  bool hneg = maxnegS > (min_pos - MARGIN);
  bool valid = hneg && (pcnt > 0);
  if (lane == 0) {
    // pass2 threshold in raw-sim units: keep/skip iff v > nthr2.
    // = max(reference neg_keep threshold, negligibility cut 0.0841*nrm).
    nthr2[row]   = fmaxf((min_pos - MARGIN) * nrm, VCUT_COEF * nrm);
    arow[row]    = inv * (SCALE_NEG * LOG2E);
    validf[row]  = valid ? 1.f : 0.f;
    hasnegf[row] = hneg ? 1.f : 0.f;
    posloss[row] = valid ? ((1.0f / SCALE_POS) * log1pf(psum)) : 0.f;
  }
}

// ---------------- pass 2: neg_sum, with wave-level early exit ----------------
__global__ __launch_bounds__(256, 2) void k_pass2(
    const short* __restrict__ pk,
    const float* __restrict__ nthr2, const float* __restrict__ arow,
    const float* __restrict__ maxnegP,
    float* __restrict__ negsumP, int N, int cps)
{
  const int lane = threadIdx.x & 63;
  const int w    = threadIdx.x >> 6;
  const int q    = lane >> 4;
  const int c    = lane & 15;
  const int cs   = blockIdx.x & (CSPLIT - 1);
  const int rbb  = blockIdx.x / CSPLIT;
  const int rowbase = rbb * RPB + w * RPW;
  const int col0 = cs * cps;

  // ---- early exit check (before any A-fragment load) ----
  {
    int myrow = rowbase + lane;
    float mn = maxnegP[(size_t)cs * N + myrow];
    float th = nthr2[myrow];
    unsigned long long bal = __ballot(mn > th);
    if (bal == 0ull) {
      negsumP[(size_t)cs * N + myrow] = 0.f;
      return;
    }
  }

  bf16x8 afr[RT][KS];
#pragma unroll
  for (int rt = 0; rt < RT; ++rt)
#pragma unroll
    for (int ks = 0; ks < KS; ++ks)
      afr[rt][ks] = *(const bf16x8*)(pk + (size_t)((rowbase >> 4) + rt) * TILE_SH + (ks * 64 + lane) * 8);

  float nthrv[RT][4], arw[RT][4], ns[RT][4];
#pragma unroll
  for (int rt = 0; rt < RT; ++rt)
#pragma unroll
    for (int rr = 0; rr < 4; ++rr) {
      int row = rowbase + rt * 16 + q * 4 + rr;
      nthrv[rt][rr] = nthr2[row];
      arw[rt][rr]   = arow[row];
      ns[rt][rr]    = 0.f;
    }

  const short* bp = pk + (size_t)(col0 >> 4) * TILE_SH + lane * 8;
  for (int ct = 0; ct < cps; ct += 16, bp += TILE_SH) {
    bf16x8 bfr[KS];
#pragma unroll
    for (int ks = 0; ks < KS; ++ks) bfr[ks] = *(const bf16x8*)(bp + ks * 512);
    f32x4 acc[RT];
#pragma unroll
    for (int rt = 0; rt < RT; ++rt) acc[rt] = 0.f;
#pragma unroll
    for (int ks = 0; ks < KS; ++ks)
#pragma unroll
      for (int rt = 0; rt < RT; ++rt)
        acc[rt] = __builtin_amdgcn_mfma_f32_16x16x32_bf16(afr[rt][ks], bfr[ks], acc[rt], 0, 0, 0);
#pragma unroll
    for (int rt = 0; rt < RT; ++rt)
#pragma unroll
      for (int rr = 0; rr < 4; ++rr) {
        float v = acc[rt][rr];
        float e = fast_exp2(fmaf(v, arw[rt][rr], BC));
        ns[rt][rr] += (v > nthrv[rt][rr]) ? e : 0.f;
      }
  }

#pragma unroll
  for (int rt = 0; rt < RT; ++rt)
#pragma unroll
    for (int rr = 0; rr < 4; ++rr) {
      float sv = ns[rt][rr];
#pragma unroll
      for (int msk = 1; msk < 16; msk <<= 1) sv += __shfl_xor(sv, msk, 64);
      if (c == 0) {
        int row = rowbase + rt * 16 + q * 4 + rr;
        negsumP[(size_t)cs * N + row] = sv;
      }
    }
}

// ---------------- final reduction (parallel) ----------------
__global__ void k_final_part(const float* __restrict__ negsumP, const float* __restrict__ posloss,
                             const float* __restrict__ validf, const float* __restrict__ hasnegf,
                             float* __restrict__ accum, int N)
{
  int i = blockIdx.x * blockDim.x + threadIdx.x;
  float lacc = 0.f, nacc = 0.f;
  if (i < N) {
    float nsum = 0.f;
    for (int cs2 = 0; cs2 < CSPLIT; ++cs2) nsum += negsumP[(size_t)cs2 * N + i];
    lacc = validf[i] * (posloss[i] + (1.0f / SCALE_NEG) * log1pf(nsum));
    nacc = 1.0f - hasnegf[i];
  }
#pragma unroll
  for (int msk = 1; msk < 64; msk <<= 1) {
    lacc += __shfl_xor(lacc, msk, 64);
    nacc += __shfl_xor(nacc, msk, 64);
  }
  __shared__ float sl[4], sn[4];
  int wid = threadIdx.x >> 6, lane = threadIdx.x & 63;
  if (lane == 0) { sl[wid] = lacc; sn[wid] = nacc; }
  __syncthreads();
  if (threadIdx.x == 0) {
    float L = sl[0] + sl[1] + sl[2] + sl[3];
    float Nn = sn[0] + sn[1] + sn[2] + sn[3];
    atomicAdd(&accum[0], L);
    atomicAdd(&accum[1], Nn);
  }
}

__global__ void k_write(const float* __restrict__ accum, float* __restrict__ out, int N) {
  out[0] = accum[0] / (float)N;
  out[1] = accum[1] * 100.0f / (float)N;
}

extern "C" void kernel_launch(void* const* d_in, const int* in_sizes, int n_in,
                              void* d_out, int out_size, void* d_ws, size_t ws_size,
                              hipStream_t stream)
{
  (void)n_in; (void)out_size; (void)ws_size;
  const float* f    = (const float*)d_in[0];
  const int*   labs = (const int*)d_in[1];
  const int Bs = in_sizes[1];      // 4096 samples
  const int N  = 2 * Bs;           // 8192 rows

  char* ws = (char*)d_ws;
  size_t off = 0;
  auto alloc = [&](size_t bytes) -> void* {
    void* p = ws + off;
    off += (bytes + 255) & ~(size_t)255;
    return p;
  };
  short* pk      = (short*)alloc((size_t)N * D * sizeof(short));
  float* sumsqP  = (float*)alloc((size_t)CSPLIT * N * sizeof(float));
  float* maxnegP = (float*)alloc((size_t)CSPLIT * N * sizeof(float));
  float* negsumP = (float*)alloc((size_t)CSPLIT * N * sizeof(float));
  float* nthr2   = (float*)alloc((size_t)N * sizeof(float));
  float* arow    = (float*)alloc((size_t)N * sizeof(float));
  float* validf  = (float*)alloc((size_t)N * sizeof(float));
  float* hasnegf = (float*)alloc((size_t)N * sizeof(float));
  float* posloss = (float*)alloc((size_t)N * sizeof(float));
  int* hist   = (int*)alloc((size_t)Bs * sizeof(int));
  int* offs   = (int*)alloc((size_t)Bs * sizeof(int));
  int* bucket = (int*)alloc((size_t)Bs * sizeof(int));
  float* accum = (float*)alloc(2 * sizeof(float));

  const int total8 = N * 24;               // 8-element chunks
  k_pack<<<(total8 + 255) / 256, 256, 0, stream>>>(f, pk, total8);
  k_buckets<<<1, 1024, 0, stream>>>(labs, hist, offs, bucket, accum, Bs);

  const int cps   = N / CSPLIT;           // 256 cols per split
  const int grid1 = (N / RPB) * CSPLIT;   // 32 * 32 = 1024 WGs
  k_pass1<<<grid1, 256, 0, stream>>>(pk, labs, sumsqP, maxnegP, N, cps);
  k_rowstats<<<N / 4, 256, 0, stream>>>(f, labs, sumsqP, maxnegP, offs, hist, bucket,
                                        nthr2, arow, validf, hasnegf, posloss, N);
  k_pass2<<<grid1, 256, 0, stream>>>(pk, nthr2, arow, maxnegP, negsumP, N, cps);
  k_final_part<<<(N + 255) / 256, 256, 0, stream>>>(negsumP, posloss, validf, hasnegf, accum, N);
  k_write<<<1, 1, 0, stream>>>(accum, (float*)d_out, N);
}

// Round 7
// 120.987 us; speedup vs baseline: 1.1239x; 1.1239x over previous
//
#include <hip/hip_runtime.h>
#include <math.h>

typedef __bf16 bf16x8 __attribute__((ext_vector_type(8)));
typedef float  f32x4  __attribute__((ext_vector_type(4)));
typedef int    int4v  __attribute__((ext_vector_type(4)));

constexpr float MARGIN    = 0.1f;
constexpr float SCALE_POS = 2.0f;
constexpr float SCALE_NEG = 50.0f;
constexpr float THRESH    = 0.5f;
constexpr float ONE_EPS   = 1.0f - 1e-5f;
constexpr float LOG2E     = 1.4426950408889634f;
constexpr float BC        = -(SCALE_NEG * THRESH * LOG2E);   // -36.0674
// elements with a*v + BC < -30 contribute < 2^-30 ~ 9e-10 each to neg_sum;
// total skipped mass <= 8192*9e-10/50 ~ 1.6e-7 on the loss (threshold 2e-2).
constexpr float VCUT_COEF = (36.0674f - 30.0f) / (SCALE_NEG * LOG2E);  // ~0.08412 (in S units)

constexpr int D      = 192;   // feature dim
constexpr int KS     = 6;     // 192 / 32 k-steps
constexpr int RT     = 4;     // row-tiles (16 rows) per wave
constexpr int RPW    = 64;    // rows per wave
constexpr int RPB    = 256;   // rows per block (4 waves)
constexpr int CSPLIT = 16;    // column splits (grid = 32 rowblocks x 16 = 512 WGs = 2/CU)

// packed fragment layout: pk[((tile*KS + ks)*64 + lane)*8] shorts, where
// tile = row/16, lane = q*16+c holds bf16[row=tile*16+c][k=ks*32+q*8 .. +8).
// One wave fragment load = contiguous 1KB global_load_dwordx4 / global_load_lds chunk.
constexpr int TILE_SH = KS * 64 * 8;   // 3072 shorts = 6KB per 16-row tile

__device__ inline short f2bf(float x) {
  unsigned u = __float_as_uint(x);
  u += 0x7fffu + ((u >> 16) & 1u);      // RNE
  return (short)(u >> 16);
}

__device__ inline float fast_exp2(float x) {
#if __has_builtin(__builtin_amdgcn_exp2f)
  return __builtin_amdgcn_exp2f(x);
#else
  return exp2f(x);
#endif
}

// async global->LDS 16B per lane: LDS dest = wave-uniform base + lane*16
__device__ inline void async_copy16(const short* g, short* l) {
  __builtin_amdgcn_global_load_lds(
      (const __attribute__((address_space(1))) unsigned int*)(const void*)g,
      (__attribute__((address_space(3))) unsigned int*)(void*)l, 16, 0, 0);
}

// pin a bf16x8 fragment in VGPRs (prevent the compiler from re-materializing
// the global load inside the K-loop -- R6 showed it reloads A per tile)
__device__ inline void pin_frag(bf16x8& v) {
  int4v t = __builtin_bit_cast(int4v, v);
  asm volatile("" : "+v"(t));
  v = __builtin_bit_cast(bf16x8, t);
}

// ---------------- fused cast fp32->bf16 + pack into fragment layout ----------------
__global__ void k_pack(const float* __restrict__ f, short* __restrict__ pk, int total8) {
  int tid = blockIdx.x * blockDim.x + threadIdx.x;
  if (tid >= total8) return;
  int row = tid / 24;
  int j   = tid - row * 24;
  const float* src = f + (size_t)tid * 8;
  float4 a = *(const float4*)(src);
  float4 b = *(const float4*)(src + 4);
  union { short s[8]; int4v v; } o;
  o.s[0] = f2bf(a.x); o.s[1] = f2bf(a.y); o.s[2] = f2bf(a.z); o.s[3] = f2bf(a.w);
  o.s[4] = f2bf(b.x); o.s[5] = f2bf(b.y); o.s[6] = f2bf(b.z); o.s[7] = f2bf(b.w);
  int idx = (((row >> 4) * KS + (j >> 2)) * 64 + (j & 3) * 16 + (row & 15)) * 8;
  *(int4v*)(pk + idx) = o.v;
}

// ---------------- buckets: hist + scan + scatter + accum-zero, one block ----------------
__global__ __launch_bounds__(1024) void k_buckets(
    const int* __restrict__ labs, int* __restrict__ hist_g, int* __restrict__ offs_g,
    int* __restrict__ bucket, float* __restrict__ accum, int n)
{
  __shared__ int histL[4096];
  __shared__ int offsL[4096];
  __shared__ int scanb[1024];
  const int t = threadIdx.x;

  if (t < 2) accum[t] = 0.f;
  for (int i = t; i < 4096; i += 1024) histL[i] = 0;
  __syncthreads();
  for (int i = t; i < n; i += 1024) atomicAdd(&histL[labs[i]], 1);
  __syncthreads();
  int base = t * 4;
  int v[4]; int ls = 0;
  for (int k = 0; k < 4; ++k) { v[k] = ls; ls += histL[base + k]; }
  scanb[t] = ls;
  __syncthreads();
  for (int o = 1; o < 1024; o <<= 1) {
    int x = (t >= o) ? scanb[t - o] : 0;
    __syncthreads();
    scanb[t] += x;
    __syncthreads();
  }
  int ebase = scanb[t] - ls;
  for (int k = 0; k < 4; ++k) {
    offsL[base + k] = ebase + v[k];
    offs_g[base + k] = ebase + v[k];
    hist_g[base + k] = histL[base + k];
  }
  __syncthreads();
  for (int i = t; i < 4096; i += 1024) histL[i] = 0;
  __syncthreads();
  for (int i = t; i < n; i += 1024) {
    int lab = labs[i];
    int p = atomicAdd(&histL[lab], 1);
    bucket[offsL[lab] + p] = i;
  }
}

// ---------------- pass 1: sumsq + max over negatives ----------------
// A resident in VGPRs (pinned); B double-buffered per-wave in LDS via async
// global_load_lds prefetch; labels staged in LDS. K-loop has zero global loads.
__global__ __launch_bounds__(256, 2) void k_pass1(
    const short* __restrict__ pk, const int* __restrict__ labs,
    float* __restrict__ sumsqP, float* __restrict__ maxnegP,
    int N, int cps)
{
  __shared__ short ldsB[4][2][KS * 512];   // 4 waves x 2 bufs x 6KB = 48KB
  __shared__ int   ldsLab[512];

  const int tid  = threadIdx.x;
  const int lane = tid & 63;
  const int w    = tid >> 6;
  const int q    = lane >> 4;
  const int c    = lane & 15;
  const int cs   = blockIdx.x & (CSPLIT - 1);
  const int rbb  = blockIdx.x / CSPLIT;
  const int rowbase = rbb * RPB + w * RPW;
  const int col0 = cs * cps;
  const int ctile0 = col0 >> 4;
  const int ntiles = cps >> 4;

  // stage this split's column labels
  for (int i = tid; i < cps; i += 256) ldsLab[i] = labs[(col0 + i) >> 1];

  // prefetch B tile 0 into buf 0 (async; overlaps the A loads below)
  {
    const short* g = pk + (size_t)ctile0 * TILE_SH + lane * 8;
#pragma unroll
    for (int k = 0; k < KS; ++k)
      async_copy16(g + k * 512, &ldsB[w][0][k * 512]);
  }

  // A fragments: load once, pin resident
  bf16x8 afr[RT][KS];
#pragma unroll
  for (int rt = 0; rt < RT; ++rt)
#pragma unroll
    for (int ks = 0; ks < KS; ++ks) {
      afr[rt][ks] = *(const bf16x8*)(pk + (size_t)((rowbase >> 4) + rt) * TILE_SH + (ks * 64 + lane) * 8);
      pin_frag(afr[rt][ks]);
    }

  int labrow[RT][4];
#pragma unroll
  for (int rt = 0; rt < RT; ++rt)
#pragma unroll
    for (int rr = 0; rr < 4; ++rr)
      labrow[rt][rr] = labs[(rowbase + rt * 16 + q * 4 + rr) >> 1];

  float ssq[RT][4], mxn[RT][4];
#pragma unroll
  for (int rt = 0; rt < RT; ++rt)
#pragma unroll
    for (int rr = 0; rr < 4; ++rr) { ssq[rt][rr] = 0.f; mxn[rt][rr] = -INFINITY; }

  __syncthreads();   // ldsLab ready

  for (int t = 0; t < ntiles; ++t) {
    // wait for this wave's prefetch of tile t to land in LDS
    asm volatile("s_waitcnt vmcnt(0)" ::: "memory");
    // prefetch tile t+1 into the other buffer (async, wave-private)
    if (t + 1 < ntiles) {
      const short* g = pk + (size_t)(ctile0 + t + 1) * TILE_SH + lane * 8;
#pragma unroll
      for (int k = 0; k < KS; ++k)
        async_copy16(g + k * 512, &ldsB[w][(t + 1) & 1][k * 512]);
    }
    const int labcol = ldsLab[t * 16 + c];
    bf16x8 bfr[KS];
#pragma unroll
    for (int ks = 0; ks < KS; ++ks)
      bfr[ks] = *(const bf16x8*)&ldsB[w][t & 1][ks * 512 + lane * 8];
    f32x4 acc[RT];
#pragma unroll
    for (int rt = 0; rt < RT; ++rt) acc[rt] = 0.f;
#pragma unroll
    for (int ks = 0; ks < KS; ++ks)
#pragma unroll
      for (int rt = 0; rt < RT; ++rt)
        acc[rt] = __builtin_amdgcn_mfma_f32_16x16x32_bf16(afr[rt][ks], bfr[ks], acc[rt], 0, 0, 0);
#pragma unroll
    for (int rt = 0; rt < RT; ++rt)
#pragma unroll
      for (int rr = 0; rr < 4; ++rr) {
        float v = acc[rt][rr];
        ssq[rt][rr] = fmaf(v, v, ssq[rt][rr]);
        float vm = (labrow[rt][rr] == labcol) ? -INFINITY : v;
        mxn[rt][rr] = fmaxf(mxn[rt][rr], vm);
      }
  }

#pragma unroll
  for (int rt = 0; rt < RT; ++rt)
#pragma unroll
    for (int rr = 0; rr < 4; ++rr) {
      float s = ssq[rt][rr], m = mxn[rt][rr];
#pragma unroll
      for (int msk = 1; msk < 16; msk <<= 1) {
        s += __shfl_xor(s, msk, 64);
        m = fmaxf(m, __shfl_xor(m, msk, 64));
      }
      if (c == 0) {
        int row = rowbase + rt * 16 + q * 4 + rr;
        sumsqP[(size_t)cs * N + row] = s;
        maxnegP[(size_t)cs * N + row] = m;
      }
    }
}

// ---------------- per-row stats: norm, min_pos (bucket dots), pos_sum, flags ----------------
__global__ void k_rowstats(
    const float* __restrict__ f, const int* __restrict__ labs,
    const float* __restrict__ sumsqP, const float* __restrict__ maxnegP,
    const int* __restrict__ offs, const int* __restrict__ hist, const int* __restrict__ bucket,
    float* __restrict__ nthr2, float* __restrict__ arow,
    float* __restrict__ validf, float* __restrict__ hasnegf, float* __restrict__ posloss,
    int N)
{
  const int lane = threadIdx.x & 63;
  const int row  = blockIdx.x * 4 + (threadIdx.x >> 6);

  float s = 0.f, m = -INFINITY;
  if (lane < CSPLIT) {
    s = sumsqP[(size_t)lane * N + row];
    m = maxnegP[(size_t)lane * N + row];
  }
#pragma unroll
  for (int msk = 1; msk < 64; msk <<= 1) {
    s += __shfl_xor(s, msk, 64);
    m = fmaxf(m, __shfl_xor(m, msk, 64));
  }
  float nrm = fmaxf(sqrtf(s), 1e-12f);
  float inv = 1.0f / nrm;
  float maxnegS = m * inv;
  float posth = fminf(ONE_EPS, maxnegS + MARGIN);

  const int lab = labs[row >> 1];
  const int beg = offs[lab], cnt = hist[lab];
  const float* fi = f + (size_t)row * D;
  float x0 = fi[lane], x1 = fi[lane + 64], x2 = fi[lane + 128];

  float minp = INFINITY, psum = 0.f; int pcnt = 0;
  for (int t = 0; t < cnt; ++t) {
    int smp = bucket[beg + t];
#pragma unroll
    for (int u = 0; u < 2; ++u) {
      const float* fj = f + (size_t)(smp * 2 + u) * D;
      float p = x0 * fj[lane] + x1 * fj[lane + 64] + x2 * fj[lane + 128];
#pragma unroll
      for (int msk = 1; msk < 64; msk <<= 1) p += __shfl_xor(p, msk, 64);
      minp = fminf(minp, p);
      float S = p * inv;
      if (S < posth) {
        psum += fast_exp2((THRESH - S) * (SCALE_POS * LOG2E));
        pcnt++;
      }
    }
  }

  float minS = minp * inv;
  float min_pos = (minS < ONE_EPS) ? minS : INFINITY;
  bool hneg = maxnegS > (min_pos - MARGIN);
  bool valid = hneg && (pcnt > 0);
  if (lane == 0) {
    // pass2 threshold in raw-sim units: keep/skip iff v > nthr2.
    // = max(reference neg_keep threshold, negligibility cut 0.0841*nrm).
    nthr2[row]   = fmaxf((min_pos - MARGIN) * nrm, VCUT_COEF * nrm);
    arow[row]    = inv * (SCALE_NEG * LOG2E);
    validf[row]  = valid ? 1.f : 0.f;
    hasnegf[row] = hneg ? 1.f : 0.f;
    posloss[row] = valid ? ((1.0f / SCALE_POS) * log1pf(psum)) : 0.f;
  }
}

// ---------------- pass 2: neg_sum, with wave-level early exit ----------------
__global__ __launch_bounds__(256, 2) void k_pass2(
    const short* __restrict__ pk,
    const float* __restrict__ nthr2, const float* __restrict__ arow,
    const float* __restrict__ maxnegP,
    float* __restrict__ negsumP, int N, int cps)
{
  const int lane = threadIdx.x & 63;
  const int w    = threadIdx.x >> 6;
  const int q    = lane >> 4;
  const int c    = lane & 15;
  const int cs   = blockIdx.x & (CSPLIT - 1);
  const int rbb  = blockIdx.x / CSPLIT;
  const int rowbase = rbb * RPB + w * RPW;
  const int col0 = cs * cps;

  // ---- early exit check (before any A-fragment load) ----
  {
    int myrow = rowbase + lane;
    float mn = maxnegP[(size_t)cs * N + myrow];
    float th = nthr2[myrow];
    unsigned long long bal = __ballot(mn > th);
    if (bal == 0ull) {
      negsumP[(size_t)cs * N + myrow] = 0.f;
      return;
    }
  }

  bf16x8 afr[RT][KS];
#pragma unroll
  for (int rt = 0; rt < RT; ++rt)
#pragma unroll
    for (int ks = 0; ks < KS; ++ks)
      afr[rt][ks] = *(const bf16x8*)(pk + (size_t)((rowbase >> 4) + rt) * TILE_SH + (ks * 64 + lane) * 8);

  float nthrv[RT][4], arw[RT][4], ns[RT][4];
#pragma unroll
  for (int rt = 0; rt < RT; ++rt)
#pragma unroll
    for (int rr = 0; rr < 4; ++rr) {
      int row = rowbase + rt * 16 + q * 4 + rr;
      nthrv[rt][rr] = nthr2[row];
      arw[rt][rr]   = arow[row];
      ns[rt][rr]    = 0.f;
    }

  const short* bp = pk + (size_t)(col0 >> 4) * TILE_SH + lane * 8;
  for (int ct = 0; ct < cps; ct += 16, bp += TILE_SH) {
    bf16x8 bfr[KS];
#pragma unroll
    for (int ks = 0; ks < KS; ++ks) bfr[ks] = *(const bf16x8*)(bp + ks * 512);
    f32x4 acc[RT];
#pragma unroll
    for (int rt = 0; rt < RT; ++rt) acc[rt] = 0.f;
#pragma unroll
    for (int ks = 0; ks < KS; ++ks)
#pragma unroll
      for (int rt = 0; rt < RT; ++rt)
        acc[rt] = __builtin_amdgcn_mfma_f32_16x16x32_bf16(afr[rt][ks], bfr[ks], acc[rt], 0, 0, 0);
#pragma unroll
    for (int rt = 0; rt < RT; ++rt)
#pragma unroll
      for (int rr = 0; rr < 4; ++rr) {
        float v = acc[rt][rr];
        float e = fast_exp2(fmaf(v, arw[rt][rr], BC));
        ns[rt][rr] += (v > nthrv[rt][rr]) ? e : 0.f;
      }
  }

#pragma unroll
  for (int rt = 0; rt < RT; ++rt)
#pragma unroll
    for (int rr = 0; rr < 4; ++rr) {
      float sv = ns[rt][rr];
#pragma unroll
      for (int msk = 1; msk < 16; msk <<= 1) sv += __shfl_xor(sv, msk, 64);
      if (c == 0) {
        int row = rowbase + rt * 16 + q * 4 + rr;
        negsumP[(size_t)cs * N + row] = sv;
      }
    }
}

// ---------------- final reduction (parallel) ----------------
__global__ void k_final_part(const float* __restrict__ negsumP, const float* __restrict__ posloss,
                             const float* __restrict__ validf, const float* __restrict__ hasnegf,
                             float* __restrict__ accum, int N)
{
  int i = blockIdx.x * blockDim.x + threadIdx.x;
  float lacc = 0.f, nacc = 0.f;
  if (i < N) {
    float nsum = 0.f;
    for (int cs2 = 0; cs2 < CSPLIT; ++cs2) nsum += negsumP[(size_t)cs2 * N + i];
    lacc = validf[i] * (posloss[i] + (1.0f / SCALE_NEG) * log1pf(nsum));
    nacc = 1.0f - hasnegf[i];
  }
#pragma unroll
  for (int msk = 1; msk < 64; msk <<= 1) {
    lacc += __shfl_xor(lacc, msk, 64);
    nacc += __shfl_xor(nacc, msk, 64);
  }
  __shared__ float sl[4], sn[4];
  int wid = threadIdx.x >> 6, lane = threadIdx.x & 63;
  if (lane == 0) { sl[wid] = lacc; sn[wid] = nacc; }
  __syncthreads();
  if (threadIdx.x == 0) {
    float L = sl[0] + sl[1] + sl[2] + sl[3];
    float Nn = sn[0] + sn[1] + sn[2] + sn[3];
    atomicAdd(&accum[0], L);
    atomicAdd(&accum[1], Nn);
  }
}

__global__ void k_write(const float* __restrict__ accum, float* __restrict__ out, int N) {
  out[0] = accum[0] / (float)N;
  out[1] = accum[1] * 100.0f / (float)N;
}

extern "C" void kernel_launch(void* const* d_in, const int* in_sizes, int n_in,
                              void* d_out, int out_size, void* d_ws, size_t ws_size,
                              hipStream_t stream)
{
  (void)n_in; (void)out_size; (void)ws_size;
  const float* f    = (const float*)d_in[0];
  const int*   labs = (const int*)d_in[1];
  const int Bs = in_sizes[1];      // 4096 samples
  const int N  = 2 * Bs;           // 8192 rows

  char* ws = (char*)d_ws;
  size_t off = 0;
  auto alloc = [&](size_t bytes) -> void* {
    void* p = ws + off;
    off += (bytes + 255) & ~(size_t)255;
    return p;
  };
  short* pk      = (short*)alloc((size_t)N * D * sizeof(short));
  float* sumsqP  = (float*)alloc((size_t)CSPLIT * N * sizeof(float));
  float* maxnegP = (float*)alloc((size_t)CSPLIT * N * sizeof(float));
  float* negsumP = (float*)alloc((size_t)CSPLIT * N * sizeof(float));
  float* nthr2   = (float*)alloc((size_t)N * sizeof(float));
  float* arow    = (float*)alloc((size_t)N * sizeof(float));
  float* validf  = (float*)alloc((size_t)N * sizeof(float));
  float* hasnegf = (float*)alloc((size_t)N * sizeof(float));
  float* posloss = (float*)alloc((size_t)N * sizeof(float));
  int* hist   = (int*)alloc((size_t)Bs * sizeof(int));
  int* offs   = (int*)alloc((size_t)Bs * sizeof(int));
  int* bucket = (int*)alloc((size_t)Bs * sizeof(int));
  float* accum = (float*)alloc(2 * sizeof(float));

  const int total8 = N * 24;               // 8-element chunks
  k_pack<<<(total8 + 255) / 256, 256, 0, stream>>>(f, pk, total8);
  k_buckets<<<1, 1024, 0, stream>>>(labs, hist, offs, bucket, accum, Bs);

  const int cps   = N / CSPLIT;           // 512 cols per split
  const int grid1 = (N / RPB) * CSPLIT;   // 32 * 16 = 512 WGs
  k_pass1<<<grid1, 256, 0, stream>>>(pk, labs, sumsqP, maxnegP, N, cps);
  k_rowstats<<<N / 4, 256, 0, stream>>>(f, labs, sumsqP, maxnegP, offs, hist, bucket,
                                        nthr2, arow, validf, hasnegf, posloss, N);
  k_pass2<<<grid1, 256, 0, stream>>>(pk, nthr2, arow, maxnegP, negsumP, N, cps);
  k_final_part<<<(N + 255) / 256, 256, 0, stream>>>(negsumP, posloss, validf, hasnegf, accum, N);
  k_write<<<1, 1, 0, stream>>>(accum, (float*)d_out, N);
}

// Round 8
// 110.974 us; speedup vs baseline: 1.2254x; 1.0902x over previous
//
#include <hip/hip_runtime.h>
#include <math.h>

typedef __bf16 bf16x8 __attribute__((ext_vector_type(8)));
typedef float  f32x4  __attribute__((ext_vector_type(4)));
typedef int    int4v  __attribute__((ext_vector_type(4)));

constexpr float MARGIN    = 0.1f;
constexpr float SCALE_POS = 2.0f;
constexpr float SCALE_NEG = 50.0f;
constexpr float THRESH    = 0.5f;
constexpr float ONE_EPS   = 1.0f - 1e-5f;
constexpr float LOG2E     = 1.4426950408889634f;
constexpr float BC        = -(SCALE_NEG * THRESH * LOG2E);   // -36.0674
// elements with a*v + BC < -30 contribute < 2^-30 ~ 9e-10 each to neg_sum;
// total skipped mass <= 8192*9e-10/50 ~ 1.6e-7 on the loss (threshold 2e-2).
constexpr float VCUT_COEF = (36.0674f - 30.0f) / (SCALE_NEG * LOG2E);  // ~0.08412 (in S units)

constexpr int D      = 192;   // feature dim
constexpr int KS     = 6;     // 192 / 32 k-steps
constexpr int RT     = 4;     // row-tiles (16 rows) per wave
constexpr int RPW    = 64;    // rows per wave
constexpr int RPB    = 256;   // rows per block (4 waves)
constexpr int CSPLIT = 16;    // column splits (grid = 32 rowblocks x 16 = 512 WGs = 2/CU)

// packed fragment layout: pk[((tile*KS + ks)*64 + lane)*8] shorts, where
// tile = row/16, lane = q*16+c holds bf16[row=tile*16+c][k=ks*32+q*8 .. +8).
// One wave fragment load = contiguous 1KB global_load_dwordx4.
constexpr int TILE_SH = KS * 64 * 8;   // 3072 shorts = 6KB per 16-row tile

__device__ inline short f2bf(float x) {
  unsigned u = __float_as_uint(x);
  u += 0x7fffu + ((u >> 16) & 1u);      // RNE
  return (short)(u >> 16);
}

__device__ inline float fast_exp2(float x) {
#if __has_builtin(__builtin_amdgcn_exp2f)
  return __builtin_amdgcn_exp2f(x);
#else
  return exp2f(x);
#endif
}

// pin a bf16x8 fragment in registers (prevent the compiler from re-materializing
// the global load inside the K-loop -- R6 showed it reloads A per tile otherwise)
__device__ inline void pin_frag(bf16x8& v) {
  int4v t = __builtin_bit_cast(int4v, v);
  asm volatile("" : "+v"(t));
  v = __builtin_bit_cast(bf16x8, t);
}

// ---------------- fused cast fp32->bf16 + pack into fragment layout ----------------
__global__ void k_pack(const float* __restrict__ f, short* __restrict__ pk, int total8) {
  int tid = blockIdx.x * blockDim.x + threadIdx.x;
  if (tid >= total8) return;
  int row = tid / 24;
  int j   = tid - row * 24;
  const float* src = f + (size_t)tid * 8;
  float4 a = *(const float4*)(src);
  float4 b = *(const float4*)(src + 4);
  union { short s[8]; int4v v; } o;
  o.s[0] = f2bf(a.x); o.s[1] = f2bf(a.y); o.s[2] = f2bf(a.z); o.s[3] = f2bf(a.w);
  o.s[4] = f2bf(b.x); o.s[5] = f2bf(b.y); o.s[6] = f2bf(b.z); o.s[7] = f2bf(b.w);
  int idx = (((row >> 4) * KS + (j >> 2)) * 64 + (j & 3) * 16 + (row & 15)) * 8;
  *(int4v*)(pk + idx) = o.v;
}

// ---------------- buckets: hist + scan + scatter + accum-zero, one block ----------------
__global__ __launch_bounds__(1024) void k_buckets(
    const int* __restrict__ labs, int* __restrict__ hist_g, int* __restrict__ offs_g,
    int* __restrict__ bucket, float* __restrict__ accum, int n)
{
  __shared__ int histL[4096];
  __shared__ int offsL[4096];
  __shared__ int scanb[1024];
  const int t = threadIdx.x;

  if (t < 2) accum[t] = 0.f;
  for (int i = t; i < 4096; i += 1024) histL[i] = 0;
  __syncthreads();
  for (int i = t; i < n; i += 1024) atomicAdd(&histL[labs[i]], 1);
  __syncthreads();
  int base = t * 4;
  int v[4]; int ls = 0;
  for (int k = 0; k < 4; ++k) { v[k] = ls; ls += histL[base + k]; }
  scanb[t] = ls;
  __syncthreads();
  for (int o = 1; o < 1024; o <<= 1) {
    int x = (t >= o) ? scanb[t - o] : 0;
    __syncthreads();
    scanb[t] += x;
    __syncthreads();
  }
  int ebase = scanb[t] - ls;
  for (int k = 0; k < 4; ++k) {
    offsL[base + k] = ebase + v[k];
    offs_g[base + k] = ebase + v[k];
    hist_g[base + k] = histL[base + k];
  }
  __syncthreads();
  for (int i = t; i < 4096; i += 1024) histL[i] = 0;
  __syncthreads();
  for (int i = t; i < n; i += 1024) {
    int lab = labs[i];
    int p = atomicAdd(&histL[lab], 1);
    bucket[offsL[lab] + p] = i;
  }
}

// ---------------- pass 1: sumsq + max over negatives ----------------
// A pinned resident; B register double-buffered, unroll-by-2 ping-pong.
// No barriers / no vmcnt(0) in the K-loop: compiler emits fine-grained
// vmcnt(N) waiting only on the buffer being consumed.
__global__ __launch_bounds__(256, 2) void k_pass1(
    const short* __restrict__ pk, const int* __restrict__ labs,
    float* __restrict__ sumsqP, float* __restrict__ maxnegP,
    int N, int cps)
{
  __shared__ int ldsLab[512];

  const int tid  = threadIdx.x;
  const int lane = tid & 63;
  const int w    = tid >> 6;
  const int q    = lane >> 4;
  const int c    = lane & 15;
  const int cs   = blockIdx.x & (CSPLIT - 1);
  const int rbb  = blockIdx.x / CSPLIT;
  const int rowbase = rbb * RPB + w * RPW;
  const int col0 = cs * cps;
  const int ctile0 = col0 >> 4;
  const int ntiles = cps >> 4;   // 32, even

  // stage this split's column labels
  for (int i = tid; i < cps; i += 256) ldsLab[i] = labs[(col0 + i) >> 1];

  // A fragments: load once, pin resident
  bf16x8 afr[RT][KS];
#pragma unroll
  for (int rt = 0; rt < RT; ++rt)
#pragma unroll
    for (int ks = 0; ks < KS; ++ks) {
      afr[rt][ks] = *(const bf16x8*)(pk + (size_t)((rowbase >> 4) + rt) * TILE_SH + (ks * 64 + lane) * 8);
      pin_frag(afr[rt][ks]);
    }

  int labrow[RT][4];
#pragma unroll
  for (int rt = 0; rt < RT; ++rt)
#pragma unroll
    for (int rr = 0; rr < 4; ++rr)
      labrow[rt][rr] = labs[(rowbase + rt * 16 + q * 4 + rr) >> 1];

  float ssq[RT][4], mxn[RT][4];
#pragma unroll
  for (int rt = 0; rt < RT; ++rt)
#pragma unroll
    for (int rr = 0; rr < 4; ++rr) { ssq[rt][rr] = 0.f; mxn[rt][rr] = -INFINITY; }

  __syncthreads();   // ldsLab ready (only barrier in the kernel)

  auto loadB = [&](int tile, bf16x8 (&bf)[KS]) {
    const short* bp = pk + (size_t)(ctile0 + tile) * TILE_SH + lane * 8;
#pragma unroll
    for (int ks = 0; ks < KS; ++ks) bf[ks] = *(const bf16x8*)(bp + ks * 512);
  };
  auto compute = [&](const bf16x8 (&bf)[KS], int t) {
    const int labcol = ldsLab[t * 16 + c];
    f32x4 acc[RT];
#pragma unroll
    for (int rt = 0; rt < RT; ++rt) acc[rt] = 0.f;
#pragma unroll
    for (int ks = 0; ks < KS; ++ks)
#pragma unroll
      for (int rt = 0; rt < RT; ++rt)
        acc[rt] = __builtin_amdgcn_mfma_f32_16x16x32_bf16(afr[rt][ks], bf[ks], acc[rt], 0, 0, 0);
#pragma unroll
    for (int rt = 0; rt < RT; ++rt)
#pragma unroll
      for (int rr = 0; rr < 4; ++rr) {
        float v = acc[rt][rr];
        ssq[rt][rr] = fmaf(v, v, ssq[rt][rr]);
        float vm = (labrow[rt][rr] == labcol) ? -INFINITY : v;
        mxn[rt][rr] = fmaxf(mxn[rt][rr], vm);
      }
  };

  bf16x8 b0[KS], b1[KS];
  loadB(0, b0);
  for (int t = 0; t < ntiles; t += 2) {
    loadB(t + 1, b1);
    compute(b0, t);
    int nx = t + 2; nx = (nx < ntiles) ? nx : 0;   // wrap: harmless reload of tile 0
    loadB(nx, b0);
    compute(b1, t + 1);
  }

#pragma unroll
  for (int rt = 0; rt < RT; ++rt)
#pragma unroll
    for (int rr = 0; rr < 4; ++rr) {
      float s = ssq[rt][rr], m = mxn[rt][rr];
#pragma unroll
      for (int msk = 1; msk < 16; msk <<= 1) {
        s += __shfl_xor(s, msk, 64);
        m = fmaxf(m, __shfl_xor(m, msk, 64));
      }
      if (c == 0) {
        int row = rowbase + rt * 16 + q * 4 + rr;
        sumsqP[(size_t)cs * N + row] = s;
        maxnegP[(size_t)cs * N + row] = m;
      }
    }
}

// ---------------- per-row stats: norm, min_pos (bucket dots), pos_sum, flags ----------------
__global__ void k_rowstats(
    const float* __restrict__ f, const int* __restrict__ labs,
    const float* __restrict__ sumsqP, const float* __restrict__ maxnegP,
    const int* __restrict__ offs, const int* __restrict__ hist, const int* __restrict__ bucket,
    float* __restrict__ nthr2, float* __restrict__ arow,
    float* __restrict__ validf, float* __restrict__ hasnegf, float* __restrict__ posloss,
    int N)
{
  const int lane = threadIdx.x & 63;
  const int row  = blockIdx.x * 4 + (threadIdx.x >> 6);

  float s = 0.f, m = -INFINITY;
  if (lane < CSPLIT) {
    s = sumsqP[(size_t)lane * N + row];
    m = maxnegP[(size_t)lane * N + row];
  }
#pragma unroll
  for (int msk = 1; msk < 64; msk <<= 1) {
    s += __shfl_xor(s, msk, 64);
    m = fmaxf(m, __shfl_xor(m, msk, 64));
  }
  float nrm = fmaxf(sqrtf(s), 1e-12f);
  float inv = 1.0f / nrm;
  float maxnegS = m * inv;
  float posth = fminf(ONE_EPS, maxnegS + MARGIN);

  const int lab = labs[row >> 1];
  const int beg = offs[lab], cnt = hist[lab];
  const float* fi = f + (size_t)row * D;
  float x0 = fi[lane], x1 = fi[lane + 64], x2 = fi[lane + 128];

  float minp = INFINITY, psum = 0.f; int pcnt = 0;
  for (int t = 0; t < cnt; ++t) {
    int smp = bucket[beg + t];
#pragma unroll
    for (int u = 0; u < 2; ++u) {
      const float* fj = f + (size_t)(smp * 2 + u) * D;
      float p = x0 * fj[lane] + x1 * fj[lane + 64] + x2 * fj[lane + 128];
#pragma unroll
      for (int msk = 1; msk < 64; msk <<= 1) p += __shfl_xor(p, msk, 64);
      minp = fminf(minp, p);
      float S = p * inv;
      if (S < posth) {
        psum += fast_exp2((THRESH - S) * (SCALE_POS * LOG2E));
        pcnt++;
      }
    }
  }

  float minS = minp * inv;
  float min_pos = (minS < ONE_EPS) ? minS : INFINITY;
  bool hneg = maxnegS > (min_pos - MARGIN);
  bool valid = hneg && (pcnt > 0);
  if (lane == 0) {
    // pass2 threshold in raw-sim units: keep/skip iff v > nthr2.
    // = max(reference neg_keep threshold, negligibility cut 0.0841*nrm).
    nthr2[row]   = fmaxf((min_pos - MARGIN) * nrm, VCUT_COEF * nrm);
    arow[row]    = inv * (SCALE_NEG * LOG2E);
    validf[row]  = valid ? 1.f : 0.f;
    hasnegf[row] = hneg ? 1.f : 0.f;
    posloss[row] = valid ? ((1.0f / SCALE_POS) * log1pf(psum)) : 0.f;
  }
}

// ---------------- pass 2: neg_sum, with wave-level early exit ----------------
__global__ __launch_bounds__(256, 2) void k_pass2(
    const short* __restrict__ pk,
    const float* __restrict__ nthr2, const float* __restrict__ arow,
    const float* __restrict__ maxnegP,
    float* __restrict__ negsumP, int N, int cps)
{
  const int lane = threadIdx.x & 63;
  const int w    = threadIdx.x >> 6;
  const int q    = lane >> 4;
  const int c    = lane & 15;
  const int cs   = blockIdx.x & (CSPLIT - 1);
  const int rbb  = blockIdx.x / CSPLIT;
  const int rowbase = rbb * RPB + w * RPW;
  const int ctile0 = (cs * cps) >> 4;
  const int ntiles = cps >> 4;

  // ---- early exit check (before any A-fragment load) ----
  {
    int myrow = rowbase + lane;
    float mn = maxnegP[(size_t)cs * N + myrow];
    float th = nthr2[myrow];
    unsigned long long bal = __ballot(mn > th);
    if (bal == 0ull) {
      negsumP[(size_t)cs * N + myrow] = 0.f;
      return;
    }
  }

  bf16x8 afr[RT][KS];
#pragma unroll
  for (int rt = 0; rt < RT; ++rt)
#pragma unroll
    for (int ks = 0; ks < KS; ++ks) {
      afr[rt][ks] = *(const bf16x8*)(pk + (size_t)((rowbase >> 4) + rt) * TILE_SH + (ks * 64 + lane) * 8);
      pin_frag(afr[rt][ks]);
    }

  float nthrv[RT][4], arw[RT][4], ns[RT][4];
#pragma unroll
  for (int rt = 0; rt < RT; ++rt)
#pragma unroll
    for (int rr = 0; rr < 4; ++rr) {
      int row = rowbase + rt * 16 + q * 4 + rr;
      nthrv[rt][rr] = nthr2[row];
      arw[rt][rr]   = arow[row];
      ns[rt][rr]    = 0.f;
    }

  auto loadB = [&](int tile, bf16x8 (&bf)[KS]) {
    const short* bp = pk + (size_t)(ctile0 + tile) * TILE_SH + lane * 8;
#pragma unroll
    for (int ks = 0; ks < KS; ++ks) bf[ks] = *(const bf16x8*)(bp + ks * 512);
  };
  auto compute = [&](const bf16x8 (&bf)[KS]) {
    f32x4 acc[RT];
#pragma unroll
    for (int rt = 0; rt < RT; ++rt) acc[rt] = 0.f;
#pragma unroll
    for (int ks = 0; ks < KS; ++ks)
#pragma unroll
      for (int rt = 0; rt < RT; ++rt)
        acc[rt] = __builtin_amdgcn_mfma_f32_16x16x32_bf16(afr[rt][ks], bf[ks], acc[rt], 0, 0, 0);
#pragma unroll
    for (int rt = 0; rt < RT; ++rt)
#pragma unroll
      for (int rr = 0; rr < 4; ++rr) {
        float v = acc[rt][rr];
        float e = fast_exp2(fmaf(v, arw[rt][rr], BC));
        ns[rt][rr] += (v > nthrv[rt][rr]) ? e : 0.f;
      }
  };

  bf16x8 b0[KS], b1[KS];
  loadB(0, b0);
  for (int t = 0; t < ntiles; t += 2) {
    loadB(t + 1, b1);
    compute(b0);
    int nx = t + 2; nx = (nx < ntiles) ? nx : 0;
    loadB(nx, b0);
    compute(b1);
  }

#pragma unroll
  for (int rt = 0; rt < RT; ++rt)
#pragma unroll
    for (int rr = 0; rr < 4; ++rr) {
      float sv = ns[rt][rr];
#pragma unroll
      for (int msk = 1; msk < 16; msk <<= 1) sv += __shfl_xor(sv, msk, 64);
      if (c == 0) {
        int row = rowbase + rt * 16 + q * 4 + rr;
        negsumP[(size_t)cs * N + row] = sv;
      }
    }
}

// ---------------- final reduction (parallel) ----------------
__global__ void k_final_part(const float* __restrict__ negsumP, const float* __restrict__ posloss,
                             const float* __restrict__ validf, const float* __restrict__ hasnegf,
                             float* __restrict__ accum, int N)
{
  int i = blockIdx.x * blockDim.x + threadIdx.x;
  float lacc = 0.f, nacc = 0.f;
  if (i < N) {
    float nsum = 0.f;
    for (int cs2 = 0; cs2 < CSPLIT; ++cs2) nsum += negsumP[(size_t)cs2 * N + i];
    lacc = validf[i] * (posloss[i] + (1.0f / SCALE_NEG) * log1pf(nsum));
    nacc = 1.0f - hasnegf[i];
  }
#pragma unroll
  for (int msk = 1; msk < 64; msk <<= 1) {
    lacc += __shfl_xor(lacc, msk, 64);
    nacc += __shfl_xor(nacc, msk, 64);
  }
  __shared__ float sl[4], sn[4];
  int wid = threadIdx.x >> 6, lane = threadIdx.x & 63;
  if (lane == 0) { sl[wid] = lacc; sn[wid] = nacc; }
  __syncthreads();
  if (threadIdx.x == 0) {
    float L = sl[0] + sl[1] + sl[2] + sl[3];
    float Nn = sn[0] + sn[1] + sn[2] + sn[3];
    atomicAdd(&accum[0], L);
    atomicAdd(&accum[1], Nn);
  }
}

__global__ void k_write(const float* __restrict__ accum, float* __restrict__ out, int N) {
  out[0] = accum[0] / (float)N;
  out[1] = accum[1] * 100.0f / (float)N;
}

extern "C" void kernel_launch(void* const* d_in, const int* in_sizes, int n_in,
                              void* d_out, int out_size, void* d_ws, size_t ws_size,
                              hipStream_t stream)
{
  (void)n_in; (void)out_size; (void)ws_size;
  const float* f    = (const float*)d_in[0];
  const int*   labs = (const int*)d_in[1];
  const int Bs = in_sizes[1];      // 4096 samples
  const int N  = 2 * Bs;           // 8192 rows

  char* ws = (char*)d_ws;
  size_t off = 0;
  auto alloc = [&](size_t bytes) -> void* {
    void* p = ws + off;
    off += (bytes + 255) & ~(size_t)255;
    return p;
  };
  short* pk      = (short*)alloc((size_t)N * D * sizeof(short));
  float* sumsqP  = (float*)alloc((size_t)CSPLIT * N * sizeof(float));
  float* maxnegP = (float*)alloc((size_t)CSPLIT * N * sizeof(float));
  float* negsumP = (float*)alloc((size_t)CSPLIT * N * sizeof(float));
  float* nthr2   = (float*)alloc((size_t)N * sizeof(float));
  float* arow    = (float*)alloc((size_t)N * sizeof(float));
  float* validf  = (float*)alloc((size_t)N * sizeof(float));
  float* hasnegf = (float*)alloc((size_t)N * sizeof(float));
  float* posloss = (float*)alloc((size_t)N * sizeof(float));
  int* hist   = (int*)alloc((size_t)Bs * sizeof(int));
  int* offs   = (int*)alloc((size_t)Bs * sizeof(int));
  int* bucket = (int*)alloc((size_t)Bs * sizeof(int));
  float* accum = (float*)alloc(2 * sizeof(float));

  const int total8 = N * 24;               // 8-element chunks
  k_pack<<<(total8 + 255) / 256, 256, 0, stream>>>(f, pk, total8);
  k_buckets<<<1, 1024, 0, stream>>>(labs, hist, offs, bucket, accum, Bs);

  const int cps   = N / CSPLIT;           // 512 cols per split
  const int grid1 = (N / RPB) * CSPLIT;   // 32 * 16 = 512 WGs
  k_pass1<<<grid1, 256, 0, stream>>>(pk, labs, sumsqP, maxnegP, N, cps);
  k_rowstats<<<N / 4, 256, 0, stream>>>(f, labs, sumsqP, maxnegP, offs, hist, bucket,
                                        nthr2, arow, validf, hasnegf, posloss, N);
  k_pass2<<<grid1, 256, 0, stream>>>(pk, nthr2, arow, maxnegP, negsumP, N, cps);
  k_final_part<<<(N + 255) / 256, 256, 0, stream>>>(negsumP, posloss, validf, hasnegf, accum, N);
  k_write<<<1, 1, 0, stream>>>(accum, (float*)d_out, N);
}

// Round 9
// 107.052 us; speedup vs baseline: 1.2703x; 1.0366x over previous
//
#include <hip/hip_runtime.h>
#include <math.h>

typedef __bf16 bf16x8 __attribute__((ext_vector_type(8)));
typedef float  f32x4  __attribute__((ext_vector_type(4)));
typedef int    int4v  __attribute__((ext_vector_type(4)));
typedef int    int8v  __attribute__((ext_vector_type(8)));

constexpr float MARGIN    = 0.1f;
constexpr float SCALE_POS = 2.0f;
constexpr float SCALE_NEG = 50.0f;
constexpr float THRESH    = 0.5f;
constexpr float ONE_EPS   = 1.0f - 1e-5f;
constexpr float LOG2E     = 1.4426950408889634f;
constexpr float BC        = -(SCALE_NEG * THRESH * LOG2E);   // -36.0674
// elements with a*v + BC < -30 contribute < 2^-30 ~ 9e-10 each to neg_sum;
// total skipped mass <= 8192*9e-10/50 ~ 1.6e-7 on the loss (threshold 2e-2).
constexpr float VCUT_COEF = (36.0674f - 30.0f) / (SCALE_NEG * LOG2E);  // ~0.08412 (in S units)

constexpr int D      = 192;   // feature dim
constexpr int KP     = 256;   // K padded to 2x128 for mfma_scale 16x16x128
constexpr int RT     = 4;     // row-tiles (16 rows) per wave
constexpr int RPW    = 64;    // rows per wave
constexpr int RPB    = 256;   // rows per block (4 waves)
constexpr int CSPLIT = 16;    // column splits (grid = 32 rowblocks x 16 = 512 WGs = 2/CU)

// fp8 packed fragment layout (K=256 = 2 frags of 128):
// pk8[tile*4096 + g*2048 + (q*16 + c)*32 + o] = fp8(f[row=tile*16+c][k=g*128+q*32+o])
// (k >= 192 zero-padded). One wave frag load = contiguous 2KB.
constexpr int TILE_B8 = 4096;   // bytes per 16-row tile
constexpr int SCALE1  = 0x7f7f7f7f;  // e8m0 = 127 -> 2^0 = 1.0 for every block

__device__ inline float fast_exp2(float x) {
#if __has_builtin(__builtin_amdgcn_exp2f)
  return __builtin_amdgcn_exp2f(x);
#else
  return exp2f(x);
#endif
}

// pin a fragment in registers (prevent re-materialization of the global load
// inside the K-loop -- R6 showed the compiler reloads A per tile otherwise)
__device__ inline void pin_frag8(int8v& v) {
  asm volatile("" : "+v"(v));
}

// ---------------- cast fp32 -> fp8 e4m3 + pack into fragment layout ----------------
// tid = r*8 + j; j indexes a 32-wide K chunk (g = j>>2, q = j&3). j >= 6 -> zeros.
__global__ void k_pack8(const float* __restrict__ f, unsigned char* __restrict__ pk8, int nrows) {
  int tid = blockIdx.x * blockDim.x + threadIdx.x;
  int r = tid >> 3, j = tid & 7;
  if (r >= nrows) return;
  float x[32];
  if (j < 6) {
    const float* src = f + (size_t)r * D + j * 32;
#pragma unroll
    for (int i = 0; i < 8; ++i) {
      float4 v = *(const float4*)(src + i * 4);
      x[i * 4 + 0] = v.x; x[i * 4 + 1] = v.y; x[i * 4 + 2] = v.z; x[i * 4 + 3] = v.w;
    }
  } else {
#pragma unroll
    for (int i = 0; i < 32; ++i) x[i] = 0.f;
  }
  union { int s[8]; int8v v; } u;
#pragma unroll
  for (int i = 0; i < 8; ++i) {
    int p = __builtin_amdgcn_cvt_pk_fp8_f32(x[i * 4 + 0], x[i * 4 + 1], 0, false);
    p     = __builtin_amdgcn_cvt_pk_fp8_f32(x[i * 4 + 2], x[i * 4 + 3], p, true);
    u.s[i] = p;
  }
  int tile = r >> 4, c = r & 15, g = j >> 2, qq = j & 3;
  *(int8v*)(pk8 + (size_t)tile * TILE_B8 + g * 2048 + (qq * 16 + c) * 32) = u.v;
}

// ---------------- buckets: hist + scan + scatter + accum-zero, one block ----------------
__global__ __launch_bounds__(1024) void k_buckets(
    const int* __restrict__ labs, int* __restrict__ hist_g, int* __restrict__ offs_g,
    int* __restrict__ bucket, float* __restrict__ accum, int n)
{
  __shared__ int histL[4096];
  __shared__ int offsL[4096];
  __shared__ int scanb[1024];
  const int t = threadIdx.x;

  if (t < 2) accum[t] = 0.f;
  for (int i = t; i < 4096; i += 1024) histL[i] = 0;
  __syncthreads();
  for (int i = t; i < n; i += 1024) atomicAdd(&histL[labs[i]], 1);
  __syncthreads();
  int base = t * 4;
  int v[4]; int ls = 0;
  for (int k = 0; k < 4; ++k) { v[k] = ls; ls += histL[base + k]; }
  scanb[t] = ls;
  __syncthreads();
  for (int o = 1; o < 1024; o <<= 1) {
    int x = (t >= o) ? scanb[t - o] : 0;
    __syncthreads();
    scanb[t] += x;
    __syncthreads();
  }
  int ebase = scanb[t] - ls;
  for (int k = 0; k < 4; ++k) {
    offsL[base + k] = ebase + v[k];
    offs_g[base + k] = ebase + v[k];
    hist_g[base + k] = histL[base + k];
  }
  __syncthreads();
  for (int i = t; i < 4096; i += 1024) histL[i] = 0;
  __syncthreads();
  for (int i = t; i < n; i += 1024) {
    int lab = labs[i];
    int p = atomicAdd(&histL[lab], 1);
    bucket[offsL[lab] + p] = i;
  }
}

// ---------------- pass 1: sumsq + max over negatives (MX-fp8 K=128, unit scales) ----------------
__global__ __launch_bounds__(256, 2) void k_pass1(
    const unsigned char* __restrict__ pk8, const int* __restrict__ labs,
    float* __restrict__ sumsqP, float* __restrict__ maxnegP,
    int N, int cps)
{
  __shared__ int ldsLab[512];

  const int tid  = threadIdx.x;
  const int lane = tid & 63;
  const int w    = tid >> 6;
  const int q    = lane >> 4;
  const int c    = lane & 15;
  const int cs   = blockIdx.x & (CSPLIT - 1);
  const int rbb  = blockIdx.x / CSPLIT;
  const int rowbase = rbb * RPB + w * RPW;
  const int col0 = cs * cps;
  const int ctile0 = col0 >> 4;
  const int ntiles = cps >> 4;   // 32, even

  for (int i = tid; i < cps; i += 256) ldsLab[i] = labs[(col0 + i) >> 1];

  // A fragments: load once, pin resident (RT x 2 x 8 VGPR = 64)
  int8v afr[RT][2];
#pragma unroll
  for (int rt = 0; rt < RT; ++rt)
#pragma unroll
    for (int g = 0; g < 2; ++g) {
      afr[rt][g] = *(const int8v*)(pk8 + (size_t)((rowbase >> 4) + rt) * TILE_B8 + g * 2048 + lane * 32);
      pin_frag8(afr[rt][g]);
    }

  int labrow[RT][4];
#pragma unroll
  for (int rt = 0; rt < RT; ++rt)
#pragma unroll
    for (int rr = 0; rr < 4; ++rr)
      labrow[rt][rr] = labs[(rowbase + rt * 16 + q * 4 + rr) >> 1];

  float ssq[RT][4], mxn[RT][4];
#pragma unroll
  for (int rt = 0; rt < RT; ++rt)
#pragma unroll
    for (int rr = 0; rr < 4; ++rr) { ssq[rt][rr] = 0.f; mxn[rt][rr] = -INFINITY; }

  __syncthreads();   // ldsLab ready (only barrier)

  auto loadB = [&](int tile, int8v (&bf)[2]) {
    const unsigned char* bp = pk8 + (size_t)(ctile0 + tile) * TILE_B8 + lane * 32;
#pragma unroll
    for (int g = 0; g < 2; ++g) bf[g] = *(const int8v*)(bp + g * 2048);
  };
  auto compute = [&](const int8v (&bf)[2], int t) {
    const int labcol = ldsLab[t * 16 + c];
    f32x4 acc[RT];
#pragma unroll
    for (int rt = 0; rt < RT; ++rt) acc[rt] = 0.f;
#pragma unroll
    for (int g = 0; g < 2; ++g)
#pragma unroll
      for (int rt = 0; rt < RT; ++rt)
        acc[rt] = __builtin_amdgcn_mfma_scale_f32_16x16x128_f8f6f4(
            afr[rt][g], bf[g], acc[rt], 0, 0, 0, SCALE1, 0, SCALE1);
#pragma unroll
    for (int rt = 0; rt < RT; ++rt)
#pragma unroll
      for (int rr = 0; rr < 4; ++rr) {
        float v = acc[rt][rr];
        ssq[rt][rr] = fmaf(v, v, ssq[rt][rr]);
        float vm = (labrow[rt][rr] == labcol) ? -INFINITY : v;
        mxn[rt][rr] = fmaxf(mxn[rt][rr], vm);
      }
  };

  int8v b0[2], b1[2];
  loadB(0, b0);
  for (int t = 0; t < ntiles; t += 2) {
    loadB(t + 1, b1);
    compute(b0, t);
    int nx = t + 2; nx = (nx < ntiles) ? nx : 0;   // wrap: harmless reload of tile 0
    loadB(nx, b0);
    compute(b1, t + 1);
  }

#pragma unroll
  for (int rt = 0; rt < RT; ++rt)
#pragma unroll
    for (int rr = 0; rr < 4; ++rr) {
      float s = ssq[rt][rr], m = mxn[rt][rr];
#pragma unroll
      for (int msk = 1; msk < 16; msk <<= 1) {
        s += __shfl_xor(s, msk, 64);
        m = fmaxf(m, __shfl_xor(m, msk, 64));
      }
      if (c == 0) {
        int row = rowbase + rt * 16 + q * 4 + rr;
        sumsqP[(size_t)cs * N + row] = s;
        maxnegP[(size_t)cs * N + row] = m;
      }
    }
}

// ---------------- per-row stats: norm, min_pos (bucket dots), pos_sum, flags ----------------
__global__ void k_rowstats(
    const float* __restrict__ f, const int* __restrict__ labs,
    const float* __restrict__ sumsqP, const float* __restrict__ maxnegP,
    const int* __restrict__ offs, const int* __restrict__ hist, const int* __restrict__ bucket,
    float* __restrict__ nthr2, float* __restrict__ arow,
    float* __restrict__ validf, float* __restrict__ hasnegf, float* __restrict__ posloss,
    int N)
{
  const int lane = threadIdx.x & 63;
  const int row  = blockIdx.x * 4 + (threadIdx.x >> 6);

  float s = 0.f, m = -INFINITY;
  if (lane < CSPLIT) {
    s = sumsqP[(size_t)lane * N + row];
    m = maxnegP[(size_t)lane * N + row];
  }
#pragma unroll
  for (int msk = 1; msk < 64; msk <<= 1) {
    s += __shfl_xor(s, msk, 64);
    m = fmaxf(m, __shfl_xor(m, msk, 64));
  }
  float nrm = fmaxf(sqrtf(s), 1e-12f);
  float inv = 1.0f / nrm;
  float maxnegS = m * inv;
  float posth = fminf(ONE_EPS, maxnegS + MARGIN);

  const int lab = labs[row >> 1];
  const int beg = offs[lab], cnt = hist[lab];
  const float* fi = f + (size_t)row * D;
  float x0 = fi[lane], x1 = fi[lane + 64], x2 = fi[lane + 128];

  float minp = INFINITY, psum = 0.f; int pcnt = 0;
  for (int t = 0; t < cnt; ++t) {
    int smp = bucket[beg + t];
#pragma unroll
    for (int u = 0; u < 2; ++u) {
      const float* fj = f + (size_t)(smp * 2 + u) * D;
      float p = x0 * fj[lane] + x1 * fj[lane + 64] + x2 * fj[lane + 128];
#pragma unroll
      for (int msk = 1; msk < 64; msk <<= 1) p += __shfl_xor(p, msk, 64);
      minp = fminf(minp, p);
      float S = p * inv;
      if (S < posth) {
        psum += fast_exp2((THRESH - S) * (SCALE_POS * LOG2E));
        pcnt++;
      }
    }
  }

  float minS = minp * inv;
  float min_pos = (minS < ONE_EPS) ? minS : INFINITY;
  bool hneg = maxnegS > (min_pos - MARGIN);
  bool valid = hneg && (pcnt > 0);
  if (lane == 0) {
    // pass2 threshold in raw-sim units: keep/skip iff v > nthr2.
    // = max(reference neg_keep threshold, negligibility cut 0.0841*nrm).
    nthr2[row]   = fmaxf((min_pos - MARGIN) * nrm, VCUT_COEF * nrm);
    arow[row]    = inv * (SCALE_NEG * LOG2E);
    validf[row]  = valid ? 1.f : 0.f;
    hasnegf[row] = hneg ? 1.f : 0.f;
    posloss[row] = valid ? ((1.0f / SCALE_POS) * log1pf(psum)) : 0.f;
  }
}

// ---------------- pass 2: neg_sum (MX-fp8), with wave-level early exit ----------------
__global__ __launch_bounds__(256, 2) void k_pass2(
    const unsigned char* __restrict__ pk8,
    const float* __restrict__ nthr2, const float* __restrict__ arow,
    const float* __restrict__ maxnegP,
    float* __restrict__ negsumP, int N, int cps)
{
  const int lane = threadIdx.x & 63;
  const int w    = threadIdx.x >> 6;
  const int q    = lane >> 4;
  const int c    = lane & 15;
  const int cs   = blockIdx.x & (CSPLIT - 1);
  const int rbb  = blockIdx.x / CSPLIT;
  const int rowbase = rbb * RPB + w * RPW;
  const int ctile0 = (cs * cps) >> 4;
  const int ntiles = cps >> 4;

  // ---- early exit check (before any A-fragment load) ----
  {
    int myrow = rowbase + lane;
    float mn = maxnegP[(size_t)cs * N + myrow];
    float th = nthr2[myrow];
    unsigned long long bal = __ballot(mn > th);
    if (bal == 0ull) {
      negsumP[(size_t)cs * N + myrow] = 0.f;
      return;
    }
  }

  int8v afr[RT][2];
#pragma unroll
  for (int rt = 0; rt < RT; ++rt)
#pragma unroll
    for (int g = 0; g < 2; ++g) {
      afr[rt][g] = *(const int8v*)(pk8 + (size_t)((rowbase >> 4) + rt) * TILE_B8 + g * 2048 + lane * 32);
      pin_frag8(afr[rt][g]);
    }

  float nthrv[RT][4], arw[RT][4], ns[RT][4];
#pragma unroll
  for (int rt = 0; rt < RT; ++rt)
#pragma unroll
    for (int rr = 0; rr < 4; ++rr) {
      int row = rowbase + rt * 16 + q * 4 + rr;
      nthrv[rt][rr] = nthr2[row];
      arw[rt][rr]   = arow[row];
      ns[rt][rr]    = 0.f;
    }

  auto loadB = [&](int tile, int8v (&bf)[2]) {
    const unsigned char* bp = pk8 + (size_t)(ctile0 + tile) * TILE_B8 + lane * 32;
#pragma unroll
    for (int g = 0; g < 2; ++g) bf[g] = *(const int8v*)(bp + g * 2048);
  };
  auto compute = [&](const int8v (&bf)[2]) {
    f32x4 acc[RT];
#pragma unroll
    for (int rt = 0; rt < RT; ++rt) acc[rt] = 0.f;
#pragma unroll
    for (int g = 0; g < 2; ++g)
#pragma unroll
      for (int rt = 0; rt < RT; ++rt)
        acc[rt] = __builtin_amdgcn_mfma_scale_f32_16x16x128_f8f6f4(
            afr[rt][g], bf[g], acc[rt], 0, 0, 0, SCALE1, 0, SCALE1);
#pragma unroll
    for (int rt = 0; rt < RT; ++rt)
#pragma unroll
      for (int rr = 0; rr < 4; ++rr) {
        float v = acc[rt][rr];
        float e = fast_exp2(fmaf(v, arw[rt][rr], BC));
        ns[rt][rr] += (v > nthrv[rt][rr]) ? e : 0.f;
      }
  };

  int8v b0[2], b1[2];
  loadB(0, b0);
  for (int t = 0; t < ntiles; t += 2) {
    loadB(t + 1, b1);
    compute(b0);
    int nx = t + 2; nx = (nx < ntiles) ? nx : 0;
    loadB(nx, b0);
    compute(b1);
  }

#pragma unroll
  for (int rt = 0; rt < RT; ++rt)
#pragma unroll
    for (int rr = 0; rr < 4; ++rr) {
      float sv = ns[rt][rr];
#pragma unroll
      for (int msk = 1; msk < 16; msk <<= 1) sv += __shfl_xor(sv, msk, 64);
      if (c == 0) {
        int row = rowbase + rt * 16 + q * 4 + rr;
        negsumP[(size_t)cs * N + row] = sv;
      }
    }
}

// ---------------- final reduction (parallel) ----------------
__global__ void k_final_part(const float* __restrict__ negsumP, const float* __restrict__ posloss,
                             const float* __restrict__ validf, const float* __restrict__ hasnegf,
                             float* __restrict__ accum, int N)
{
  int i = blockIdx.x * blockDim.x + threadIdx.x;
  float lacc = 0.f, nacc = 0.f;
  if (i < N) {
    float nsum = 0.f;
    for (int cs2 = 0; cs2 < CSPLIT; ++cs2) nsum += negsumP[(size_t)cs2 * N + i];
    lacc = validf[i] * (posloss[i] + (1.0f / SCALE_NEG) * log1pf(nsum));
    nacc = 1.0f - hasnegf[i];
  }
#pragma unroll
  for (int msk = 1; msk < 64; msk <<= 1) {
    lacc += __shfl_xor(lacc, msk, 64);
    nacc += __shfl_xor(nacc, msk, 64);
  }
  __shared__ float sl[4], sn[4];
  int wid = threadIdx.x >> 6, lane = threadIdx.x & 63;
  if (lane == 0) { sl[wid] = lacc; sn[wid] = nacc; }
  __syncthreads();
  if (threadIdx.x == 0) {
    float L = sl[0] + sl[1] + sl[2] + sl[3];
    float Nn = sn[0] + sn[1] + sn[2] + sn[3];
    atomicAdd(&accum[0], L);
    atomicAdd(&accum[1], Nn);
  }
}

__global__ void k_write(const float* __restrict__ accum, float* __restrict__ out, int N) {
  out[0] = accum[0] / (float)N;
  out[1] = accum[1] * 100.0f / (float)N;
}

extern "C" void kernel_launch(void* const* d_in, const int* in_sizes, int n_in,
                              void* d_out, int out_size, void* d_ws, size_t ws_size,
                              hipStream_t stream)
{
  (void)n_in; (void)out_size; (void)ws_size;
  const float* f    = (const float*)d_in[0];
  const int*   labs = (const int*)d_in[1];
  const int Bs = in_sizes[1];      // 4096 samples
  const int N  = 2 * Bs;           // 8192 rows

  char* ws = (char*)d_ws;
  size_t off = 0;
  auto alloc = [&](size_t bytes) -> void* {
    void* p = ws + off;
    off += (bytes + 255) & ~(size_t)255;
    return p;
  };
  unsigned char* pk8 = (unsigned char*)alloc((size_t)N * KP);
  float* sumsqP  = (float*)alloc((size_t)CSPLIT * N * sizeof(float));
  float* maxnegP = (float*)alloc((size_t)CSPLIT * N * sizeof(float));
  float* negsumP = (float*)alloc((size_t)CSPLIT * N * sizeof(float));
  float* nthr2   = (float*)alloc((size_t)N * sizeof(float));
  float* arow    = (float*)alloc((size_t)N * sizeof(float));
  float* validf  = (float*)alloc((size_t)N * sizeof(float));
  float* hasnegf = (float*)alloc((size_t)N * sizeof(float));
  float* posloss = (float*)alloc((size_t)N * sizeof(float));
  int* hist   = (int*)alloc((size_t)Bs * sizeof(int));
  int* offs   = (int*)alloc((size_t)Bs * sizeof(int));
  int* bucket = (int*)alloc((size_t)Bs * sizeof(int));
  float* accum = (float*)alloc(2 * sizeof(float));

  const int totalp = N * 8;                // 32-wide K chunks
  k_pack8<<<(totalp + 255) / 256, 256, 0, stream>>>(f, pk8, N);
  k_buckets<<<1, 1024, 0, stream>>>(labs, hist, offs, bucket, accum, Bs);

  const int cps   = N / CSPLIT;           // 512 cols per split
  const int grid1 = (N / RPB) * CSPLIT;   // 32 * 16 = 512 WGs
  k_pass1<<<grid1, 256, 0, stream>>>(pk8, labs, sumsqP, maxnegP, N, cps);
  k_rowstats<<<N / 4, 256, 0, stream>>>(f, labs, sumsqP, maxnegP, offs, hist, bucket,
                                        nthr2, arow, validf, hasnegf, posloss, N);
  k_pass2<<<grid1, 256, 0, stream>>>(pk8, nthr2, arow, maxnegP, negsumP, N, cps);
  k_final_part<<<(N + 255) / 256, 256, 0, stream>>>(negsumP, posloss, validf, hasnegf, accum, N);
  k_write<<<1, 1, 0, stream>>>(accum, (float*)d_out, N);
}

// Round 10
// 100.357 us; speedup vs baseline: 1.3550x; 1.0667x over previous
//
#include <hip/hip_runtime.h>
#include <math.h>

typedef float  f32x4  __attribute__((ext_vector_type(4)));
typedef int    int4v  __attribute__((ext_vector_type(4)));
typedef int    int8v  __attribute__((ext_vector_type(8)));

constexpr float MARGIN    = 0.1f;
constexpr float SCALE_POS = 2.0f;
constexpr float SCALE_NEG = 50.0f;
constexpr float THRESH    = 0.5f;
constexpr float ONE_EPS   = 1.0f - 1e-5f;
constexpr float LOG2E     = 1.4426950408889634f;
constexpr float BC        = -(SCALE_NEG * THRESH * LOG2E);   // -36.0674
// elements with a*v + BC < -30 contribute < 2^-30 ~ 9e-10 each to neg_sum;
// total skipped mass <= 8192*9e-10/50 ~ 1.6e-7 on the loss (threshold 2e-2).
constexpr float VCUT_COEF = (36.0674f - 30.0f) / (SCALE_NEG * LOG2E);  // ~0.08412 (in S units)

constexpr int D      = 192;   // feature dim
constexpr int KP     = 256;   // K padded to 2x128 for mfma_scale 16x16x128
constexpr int RT     = 4;     // row-tiles (16 rows) per wave
constexpr int RPW    = 64;    // rows per wave
constexpr int RPB    = 256;   // rows per block (4 waves)
constexpr int CSPLIT = 16;    // column splits (grid = 32 rowblocks x 16 = 512 WGs = 2/CU)

// fp8 packed fragment layout (K=256 = 2 frags of 128):
// pk8[tile*4096 + g*2048 + (q*16 + c)*32 + o] = fp8(f[row=tile*16+c][k=g*128+q*32+o])
// (k >= 192 zero-padded). One wave frag load = contiguous 2KB.
constexpr int TILE_B8 = 4096;   // bytes per 16-row tile
constexpr int SCALE1  = 0x7f7f7f7f;  // e8m0 = 127 -> 2^0 = 1.0 for every block

__device__ inline float fast_exp2(float x) {
#if __has_builtin(__builtin_amdgcn_exp2f)
  return __builtin_amdgcn_exp2f(x);
#else
  return exp2f(x);
#endif
}

// pin a fragment in registers (prevent re-materialization of the global load
// inside the K-loop -- R6 showed the compiler reloads A per tile otherwise)
__device__ inline void pin_frag8(int8v& v) {
  asm volatile("" : "+v"(v));
}

// ---------------- prep: fp32->fp8 pack (blocks 0..63) + buckets (block 64) ----------------
__global__ __launch_bounds__(1024) void k_prep(
    const float* __restrict__ f, unsigned char* __restrict__ pk8, int nrows,
    const int* __restrict__ labs, int* __restrict__ hist_g, int* __restrict__ offs_g,
    int* __restrict__ bucket, float* __restrict__ accum, int n)
{
  if (blockIdx.x < 64) {
    // ---- pack: tid = r*8 + j; j indexes a 32-wide K chunk (g=j>>2, q=j&3); j>=6 -> zeros
    int gid = blockIdx.x * 1024 + threadIdx.x;
    int r = gid >> 3, j = gid & 7;
    if (r >= nrows) return;
    float x[32];
    if (j < 6) {
      const float* src = f + (size_t)r * D + j * 32;
#pragma unroll
      for (int i = 0; i < 8; ++i) {
        float4 v = *(const float4*)(src + i * 4);
        x[i * 4 + 0] = v.x; x[i * 4 + 1] = v.y; x[i * 4 + 2] = v.z; x[i * 4 + 3] = v.w;
      }
    } else {
#pragma unroll
      for (int i = 0; i < 32; ++i) x[i] = 0.f;
    }
    union { int s[8]; int8v v; } u;
#pragma unroll
    for (int i = 0; i < 8; ++i) {
      int p = __builtin_amdgcn_cvt_pk_fp8_f32(x[i * 4 + 0], x[i * 4 + 1], 0, false);
      p     = __builtin_amdgcn_cvt_pk_fp8_f32(x[i * 4 + 2], x[i * 4 + 3], p, true);
      u.s[i] = p;
    }
    int tile = r >> 4, c = r & 15, g = j >> 2, qq = j & 3;
    *(int8v*)(pk8 + (size_t)tile * TILE_B8 + g * 2048 + (qq * 16 + c) * 32) = u.v;
    return;
  }

  // ---- buckets: hist + scan + scatter + accum zero (single block)
  __shared__ int histL[4096];
  __shared__ int offsL[4096];
  __shared__ int scanb[1024];
  const int t = threadIdx.x;

  if (t < 3) accum[t] = 0.f;     // [0]=loss sum, [1]=no-neg count, [2]=ticket
  for (int i = t; i < 4096; i += 1024) histL[i] = 0;
  __syncthreads();
  for (int i = t; i < n; i += 1024) atomicAdd(&histL[labs[i]], 1);
  __syncthreads();
  int base = t * 4;
  int v[4]; int ls = 0;
  for (int k = 0; k < 4; ++k) { v[k] = ls; ls += histL[base + k]; }
  scanb[t] = ls;
  __syncthreads();
  for (int o = 1; o < 1024; o <<= 1) {
    int x = (t >= o) ? scanb[t - o] : 0;
    __syncthreads();
    scanb[t] += x;
    __syncthreads();
  }
  int ebase = scanb[t] - ls;
  for (int k = 0; k < 4; ++k) {
    offsL[base + k] = ebase + v[k];
    offs_g[base + k] = ebase + v[k];
    hist_g[base + k] = histL[base + k];
  }
  __syncthreads();
  for (int i = t; i < 4096; i += 1024) histL[i] = 0;
  __syncthreads();
  for (int i = t; i < n; i += 1024) {
    int lab = labs[i];
    int p = atomicAdd(&histL[lab], 1);
    bucket[offsL[lab] + p] = i;
  }
}

// ---------------- pass 1: sumsq + max over negatives (MX-fp8 K=128, unit scales) ----------------
// A pinned resident; B quad-buffered (prefetch distance 2), unroll-by-4 rotation.
__global__ __launch_bounds__(256, 2) void k_pass1(
    const unsigned char* __restrict__ pk8, const int* __restrict__ labs,
    float* __restrict__ sumsqP, float* __restrict__ maxnegP,
    int N, int cps)
{
  __shared__ int ldsLab[512];

  const int tid  = threadIdx.x;
  const int lane = tid & 63;
  const int w    = tid >> 6;
  const int q    = lane >> 4;
  const int c    = lane & 15;
  const int cs   = blockIdx.x & (CSPLIT - 1);
  const int rbb  = blockIdx.x / CSPLIT;
  const int rowbase = rbb * RPB + w * RPW;
  const int col0 = cs * cps;
  const int ctile0 = col0 >> 4;
  const int ntiles = cps >> 4;   // 32, divisible by 4

  for (int i = tid; i < cps; i += 256) ldsLab[i] = labs[(col0 + i) >> 1];

  // A fragments: load once, pin resident (RT x 2 x 8 VGPR = 64)
  int8v afr[RT][2];
#pragma unroll
  for (int rt = 0; rt < RT; ++rt)
#pragma unroll
    for (int g = 0; g < 2; ++g) {
      afr[rt][g] = *(const int8v*)(pk8 + (size_t)((rowbase >> 4) + rt) * TILE_B8 + g * 2048 + lane * 32);
      pin_frag8(afr[rt][g]);
    }

  int labrow[RT][4];
#pragma unroll
  for (int rt = 0; rt < RT; ++rt)
#pragma unroll
    for (int rr = 0; rr < 4; ++rr)
      labrow[rt][rr] = labs[(rowbase + rt * 16 + q * 4 + rr) >> 1];

  float ssq[RT][4], mxn[RT][4];
#pragma unroll
  for (int rt = 0; rt < RT; ++rt)
#pragma unroll
    for (int rr = 0; rr < 4; ++rr) { ssq[rt][rr] = 0.f; mxn[rt][rr] = -INFINITY; }

  __syncthreads();   // ldsLab ready (only barrier)

  auto loadB = [&](int tile, int8v (&bf)[2]) {
    const unsigned char* bp = pk8 + (size_t)(ctile0 + tile) * TILE_B8 + lane * 32;
#pragma unroll
    for (int g = 0; g < 2; ++g) bf[g] = *(const int8v*)(bp + g * 2048);
  };
  auto compute = [&](const int8v (&bf)[2], int t) {
    const int labcol = ldsLab[t * 16 + c];
    f32x4 acc[RT];
#pragma unroll
    for (int rt = 0; rt < RT; ++rt) acc[rt] = 0.f;
#pragma unroll
    for (int g = 0; g < 2; ++g)
#pragma unroll
      for (int rt = 0; rt < RT; ++rt)
        acc[rt] = __builtin_amdgcn_mfma_scale_f32_16x16x128_f8f6f4(
            afr[rt][g], bf[g], acc[rt], 0, 0, 0, SCALE1, 0, SCALE1);
#pragma unroll
    for (int rt = 0; rt < RT; ++rt)
#pragma unroll
      for (int rr = 0; rr < 4; ++rr) {
        float v = acc[rt][rr];
        ssq[rt][rr] = fmaf(v, v, ssq[rt][rr]);
        float vm = (labrow[rt][rr] == labcol) ? -INFINITY : v;
        mxn[rt][rr] = fmaxf(mxn[rt][rr], vm);
      }
  };

  auto wrap = [&](int x) { return (x < ntiles) ? x : 0; };
  int8v b0[2], b1[2], b2[2], b3[2];
  loadB(0, b0);
  loadB(1, b1);
  for (int t = 0; t < ntiles; t += 4) {
    loadB(wrap(t + 2), b2); compute(b0, t);
    loadB(wrap(t + 3), b3); compute(b1, t + 1);
    loadB(wrap(t + 4), b0); compute(b2, t + 2);
    loadB(wrap(t + 5), b1); compute(b3, t + 3);
  }

#pragma unroll
  for (int rt = 0; rt < RT; ++rt)
#pragma unroll
    for (int rr = 0; rr < 4; ++rr) {
      float s = ssq[rt][rr], m = mxn[rt][rr];
#pragma unroll
      for (int msk = 1; msk < 16; msk <<= 1) {
        s += __shfl_xor(s, msk, 64);
        m = fmaxf(m, __shfl_xor(m, msk, 64));
      }
      if (c == 0) {
        int row = rowbase + rt * 16 + q * 4 + rr;
        sumsqP[(size_t)cs * N + row] = s;
        maxnegP[(size_t)cs * N + row] = m;
      }
    }
}

// ---------------- per-row stats: norm, min_pos (bucket dots), pos_sum, flags ----------------
__global__ void k_rowstats(
    const float* __restrict__ f, const int* __restrict__ labs,
    const float* __restrict__ sumsqP, const float* __restrict__ maxnegP,
    const int* __restrict__ offs, const int* __restrict__ hist, const int* __restrict__ bucket,
    float* __restrict__ nthr2, float* __restrict__ arow,
    float* __restrict__ validf, float* __restrict__ hasnegf, float* __restrict__ posloss,
    int N)
{
  const int lane = threadIdx.x & 63;
  const int row  = blockIdx.x * 4 + (threadIdx.x >> 6);

  float s = 0.f, m = -INFINITY;
  if (lane < CSPLIT) {
    s = sumsqP[(size_t)lane * N + row];
    m = maxnegP[(size_t)lane * N + row];
  }
#pragma unroll
  for (int msk = 1; msk < 64; msk <<= 1) {
    s += __shfl_xor(s, msk, 64);
    m = fmaxf(m, __shfl_xor(m, msk, 64));
  }
  float nrm = fmaxf(sqrtf(s), 1e-12f);
  float inv = 1.0f / nrm;
  float maxnegS = m * inv;
  float posth = fminf(ONE_EPS, maxnegS + MARGIN);

  const int lab = labs[row >> 1];
  const int beg = offs[lab], cnt = hist[lab];
  const float* fi = f + (size_t)row * D;
  float x0 = fi[lane], x1 = fi[lane + 64], x2 = fi[lane + 128];

  float minp = INFINITY, psum = 0.f; int pcnt = 0;
  for (int t = 0; t < cnt; ++t) {
    int smp = bucket[beg + t];
#pragma unroll
    for (int u = 0; u < 2; ++u) {
      const float* fj = f + (size_t)(smp * 2 + u) * D;
      float p = x0 * fj[lane] + x1 * fj[lane + 64] + x2 * fj[lane + 128];
#pragma unroll
      for (int msk = 1; msk < 64; msk <<= 1) p += __shfl_xor(p, msk, 64);
      minp = fminf(minp, p);
      float S = p * inv;
      if (S < posth) {
        psum += fast_exp2((THRESH - S) * (SCALE_POS * LOG2E));
        pcnt++;
      }
    }
  }

  float minS = minp * inv;
  float min_pos = (minS < ONE_EPS) ? minS : INFINITY;
  bool hneg = maxnegS > (min_pos - MARGIN);
  bool valid = hneg && (pcnt > 0);
  if (lane == 0) {
    // pass2 threshold in raw-sim units: keep/skip iff v > nthr2.
    // = max(reference neg_keep threshold, negligibility cut 0.0841*nrm).
    nthr2[row]   = fmaxf((min_pos - MARGIN) * nrm, VCUT_COEF * nrm);
    arow[row]    = inv * (SCALE_NEG * LOG2E);
    validf[row]  = valid ? 1.f : 0.f;
    hasnegf[row] = hneg ? 1.f : 0.f;
    posloss[row] = valid ? ((1.0f / SCALE_POS) * log1pf(psum)) : 0.f;
  }
}

// ---------------- pass 2: neg_sum (MX-fp8), with wave-level early exit ----------------
__global__ __launch_bounds__(256, 2) void k_pass2(
    const unsigned char* __restrict__ pk8,
    const float* __restrict__ nthr2, const float* __restrict__ arow,
    const float* __restrict__ maxnegP,
    float* __restrict__ negsumP, int N, int cps)
{
  const int lane = threadIdx.x & 63;
  const int w    = threadIdx.x >> 6;
  const int q    = lane >> 4;
  const int c    = lane & 15;
  const int cs   = blockIdx.x & (CSPLIT - 1);
  const int rbb  = blockIdx.x / CSPLIT;
  const int rowbase = rbb * RPB + w * RPW;
  const int ctile0 = (cs * cps) >> 4;
  const int ntiles = cps >> 4;

  // ---- early exit check (before any A-fragment load) ----
  {
    int myrow = rowbase + lane;
    float mn = maxnegP[(size_t)cs * N + myrow];
    float th = nthr2[myrow];
    unsigned long long bal = __ballot(mn > th);
    if (bal == 0ull) {
      negsumP[(size_t)cs * N + myrow] = 0.f;
      return;
    }
  }

  int8v afr[RT][2];
#pragma unroll
  for (int rt = 0; rt < RT; ++rt)
#pragma unroll
    for (int g = 0; g < 2; ++g) {
      afr[rt][g] = *(const int8v*)(pk8 + (size_t)((rowbase >> 4) + rt) * TILE_B8 + g * 2048 + lane * 32);
      pin_frag8(afr[rt][g]);
    }

  float nthrv[RT][4], arw[RT][4], ns[RT][4];
#pragma unroll
  for (int rt = 0; rt < RT; ++rt)
#pragma unroll
    for (int rr = 0; rr < 4; ++rr) {
      int row = rowbase + rt * 16 + q * 4 + rr;
      nthrv[rt][rr] = nthr2[row];
      arw[rt][rr]   = arow[row];
      ns[rt][rr]    = 0.f;
    }

  auto loadB = [&](int tile, int8v (&bf)[2]) {
    const unsigned char* bp = pk8 + (size_t)(ctile0 + tile) * TILE_B8 + lane * 32;
#pragma unroll
    for (int g = 0; g < 2; ++g) bf[g] = *(const int8v*)(bp + g * 2048);
  };
  auto compute = [&](const int8v (&bf)[2]) {
    f32x4 acc[RT];
#pragma unroll
    for (int rt = 0; rt < RT; ++rt) acc[rt] = 0.f;
#pragma unroll
    for (int g = 0; g < 2; ++g)
#pragma unroll
      for (int rt = 0; rt < RT; ++rt)
        acc[rt] = __builtin_amdgcn_mfma_scale_f32_16x16x128_f8f6f4(
            afr[rt][g], bf[g], acc[rt], 0, 0, 0, SCALE1, 0, SCALE1);
#pragma unroll
    for (int rt = 0; rt < RT; ++rt)
#pragma unroll
      for (int rr = 0; rr < 4; ++rr) {
        float v = acc[rt][rr];
        float e = fast_exp2(fmaf(v, arw[rt][rr], BC));
        ns[rt][rr] += (v > nthrv[rt][rr]) ? e : 0.f;
      }
  };

  int8v b0[2], b1[2];
  loadB(0, b0);
  for (int t = 0; t < ntiles; t += 2) {
    loadB(t + 1, b1);
    compute(b0);
    int nx = t + 2; nx = (nx < ntiles) ? nx : 0;
    loadB(nx, b0);
    compute(b1);
  }

#pragma unroll
  for (int rt = 0; rt < RT; ++rt)
#pragma unroll
    for (int rr = 0; rr < 4; ++rr) {
      float sv = ns[rt][rr];
#pragma unroll
      for (int msk = 1; msk < 16; msk <<= 1) sv += __shfl_xor(sv, msk, 64);
      if (c == 0) {
        int row = rowbase + rt * 16 + q * 4 + rr;
        negsumP[(size_t)cs * N + row] = sv;
      }
    }
}

// ---------------- final reduction + last-block writeback (atomic ticket) ----------------
__global__ void k_final(const float* __restrict__ negsumP, const float* __restrict__ posloss,
                        const float* __restrict__ validf, const float* __restrict__ hasnegf,
                        float* __restrict__ accum, float* __restrict__ out, int N)
{
  int i = blockIdx.x * blockDim.x + threadIdx.x;
  float lacc = 0.f, nacc = 0.f;
  if (i < N) {
    float nsum = 0.f;
    for (int cs2 = 0; cs2 < CSPLIT; ++cs2) nsum += negsumP[(size_t)cs2 * N + i];
    lacc = validf[i] * (posloss[i] + (1.0f / SCALE_NEG) * log1pf(nsum));
    nacc = 1.0f - hasnegf[i];
  }
#pragma unroll
  for (int msk = 1; msk < 64; msk <<= 1) {
    lacc += __shfl_xor(lacc, msk, 64);
    nacc += __shfl_xor(nacc, msk, 64);
  }
  __shared__ float sl[4], sn[4];
  __shared__ bool isLast;
  int wid = threadIdx.x >> 6, lane = threadIdx.x & 63;
  if (lane == 0) { sl[wid] = lacc; sn[wid] = nacc; }
  __syncthreads();
  if (threadIdx.x == 0) {
    float L = sl[0] + sl[1] + sl[2] + sl[3];
    float Nn = sn[0] + sn[1] + sn[2] + sn[3];
    atomicAdd(&accum[0], L);
    atomicAdd(&accum[1], Nn);
    __threadfence();
    int tkt = atomicAdd((int*)&accum[2], 1);
    isLast = (tkt == (int)gridDim.x - 1);
  }
  __syncthreads();
  if (isLast && threadIdx.x == 0) {
    __threadfence();
    out[0] = accum[0] / (float)N;
    out[1] = accum[1] * 100.0f / (float)N;
  }
}

extern "C" void kernel_launch(void* const* d_in, const int* in_sizes, int n_in,
                              void* d_out, int out_size, void* d_ws, size_t ws_size,
                              hipStream_t stream)
{
  (void)n_in; (void)out_size; (void)ws_size;
  const float* f    = (const float*)d_in[0];
  const int*   labs = (const int*)d_in[1];
  const int Bs = in_sizes[1];      // 4096 samples
  const int N  = 2 * Bs;           // 8192 rows

  char* ws = (char*)d_ws;
  size_t off = 0;
  auto alloc = [&](size_t bytes) -> void* {
    void* p = ws + off;
    off += (bytes + 255) & ~(size_t)255;
    return p;
  };
  unsigned char* pk8 = (unsigned char*)alloc((size_t)N * KP);
  float* sumsqP  = (float*)alloc((size_t)CSPLIT * N * sizeof(float));
  float* maxnegP = (float*)alloc((size_t)CSPLIT * N * sizeof(float));
  float* negsumP = (float*)alloc((size_t)CSPLIT * N * sizeof(float));
  float* nthr2   = (float*)alloc((size_t)N * sizeof(float));
  float* arow    = (float*)alloc((size_t)N * sizeof(float));
  float* validf  = (float*)alloc((size_t)N * sizeof(float));
  float* hasnegf = (float*)alloc((size_t)N * sizeof(float));
  float* posloss = (float*)alloc((size_t)N * sizeof(float));
  int* hist   = (int*)alloc((size_t)Bs * sizeof(int));
  int* offs   = (int*)alloc((size_t)Bs * sizeof(int));
  int* bucket = (int*)alloc((size_t)Bs * sizeof(int));
  float* accum = (float*)alloc(4 * sizeof(float));   // loss, no-neg count, ticket

  // prep: 64 pack blocks (N*8 = 65536 threads) + 1 buckets block
  k_prep<<<65, 1024, 0, stream>>>(f, pk8, N, labs, hist, offs, bucket, accum, Bs);

  const int cps   = N / CSPLIT;           // 512 cols per split
  const int grid1 = (N / RPB) * CSPLIT;   // 32 * 16 = 512 WGs
  k_pass1<<<grid1, 256, 0, stream>>>(pk8, labs, sumsqP, maxnegP, N, cps);
  k_rowstats<<<N / 4, 256, 0, stream>>>(f, labs, sumsqP, maxnegP, offs, hist, bucket,
                                        nthr2, arow, validf, hasnegf, posloss, N);
  k_pass2<<<grid1, 256, 0, stream>>>(pk8, nthr2, arow, maxnegP, negsumP, N, cps);
  k_final<<<N / 256, 256, 0, stream>>>(negsumP, posloss, validf, hasnegf, accum, (float*)d_out, N);
}